// Round 3
// baseline (5581.139 us; speedup 1.0000x reference)
//
#include <hip/hip_runtime.h>

// PSGIN forward on MI355X. fp32 I/O.
// R11 (630us): stage0 merge. R13 (628us): poly tanh. R14 (630us, NEUTRAL): P^2 algebra +
// aux absorption — fit: T = 9us/link * links + 0.068us/MFLOP. ~270us is per-link fixed cost.
// R15 FAILED: persistent kernel, absmax 72 + 237s wall — VGPR >256 (no min-occupancy bound)
// -> 1 block/CU -> only 256/512 blocks resident -> barrier spin-break -> stale data.
// R16: __launch_bounds__(256, 2) forces <=256 VGPR (2 blocks/CU by regalloc contract);
// LDS 51.7KB*2 = 103KB <= 160KB. 512 blocks = exactly 2/CU -> co-residency guaranteed.

constexpr int B = 8, T = 24, N = 207, F = 16, H = 64, DH = 16;
constexpr int PS = 208; // padded stride for N x N matrices
constexpr float ALPHA = 0.05f, BETA = 0.95f, GAMMA = 0.95f, TA = 2.0f;
constexpr int NF = N * F;      // 3312
constexpr int BNF = B * N * F; // 26496

__device__ __forceinline__ float tanh_fast(float x) { float e = __expf(2.f * x); return 1.f - 2.f / (e + 1.f); }
__device__ __forceinline__ float sigm(float x) { return 1.f / (1.f + __expf(-x)); }
// cubic/quintic series tanh: x*(1 + x2*(-1/3 + (2/15)x2)); |err|<1e-3 for |x|<0.6.
__device__ __forceinline__ float tanh_poly(float x) {
    float x2 = x * x;
    float c = __builtin_fmaf(x2, 0.13333333f, -0.33333333f);
    return x * __builtin_fmaf(x2, c, 1.f);
}

// =============== stage 0: Ts transpose + A2 = (adj@adj)^T + attention scores ===============
__global__ __launch_bounds__(256) void k_stage0(
    const float* __restrict__ adj, const float* __restrict__ inp,
    const float* __restrict__ Wq, const float* __restrict__ Wk,
    const float* __restrict__ kb, const float* __restrict__ sw_,
    float* __restrict__ Ts, float* __restrict__ A2,
    float* __restrict__ attnT, float* __restrict__ rsum)
{
    __shared__ __align__(16) float smem[7424];
    int bid = blockIdx.x, tid = threadIdx.x;
    if (bid < 49) {
        int vb = (bid % 7) * 32, wb = (bid / 7) * 32;
        float* sA = smem;          // [32][33]
        float* sB = smem + 1056;   // [32][33]
        float acc[4] = {0, 0, 0, 0};
        int i0 = tid >> 5, j = tid & 31;
        for (int u0 = 0; u0 < N; u0 += 32) {
            __syncthreads();
            for (int l = tid; l < 1024; l += 256) {
                int i = l >> 5, jj = l & 31;
                int v = vb + i, u = u0 + jj;
                sA[i * 33 + jj] = (v < N && u < N) ? adj[v * N + u] : 0.f;
                int uu = u0 + i, w = wb + jj;
                sB[i * 33 + jj] = (uu < N && w < N) ? adj[uu * N + w] : 0.f;
            }
            __syncthreads();
#pragma unroll 8
            for (int u = 0; u < 32; u++) {
                float bv = sB[u * 33 + j];
#pragma unroll
                for (int k = 0; k < 4; k++) acc[k] += sA[(i0 + k * 8) * 33 + u] * bv;
            }
        }
#pragma unroll
        for (int k = 0; k < 4; k++) {
            int v = vb + i0 + k * 8, w = wb + j;
            if (v < N && w < N) A2[(size_t)w * PS + v] = acc[k];
        }
    } else if (bid < 217) {
        int i = (bid - 49) * 256 + tid;
        if (i < N * N) {
            int w = i / N, v = i % N;
            Ts[(size_t)w * PS + v] = adj[v * N + w];
        }
    } else {
        int idx = bid - 217;
        int bt = idx / 49, rem = idx % 49;
        int n0 = (rem % 7) * 32, m0 = (rem / 7) * 32;
        int b = bt >> 2, tau = bt & 3;
        int ti = tid >> 4, tj = tid & 15;
        float* sQ = smem;            // 32*65
        float* sK = smem + 2080;     // 32*65
        float* sWq = smem + 4160;    // 16*64
        float* sWk = smem + 5184;    // 16*64
        float* sXq = smem + 6208;    // 32*17
        float* sXk = smem + 6752;    // 32*17
        float* ssw = smem + 7296;    // 64
        float* skb = smem + 7360;    // 64
        const float* xq = inp + ((size_t)(b * T + (T - 1))) * NF;
        const float* xk = inp + ((size_t)(b * T + 20 + tau)) * NF;
        {
            float4 wq4 = *(const float4*)&Wq[tid * 4];
            float4 wk4 = *(const float4*)&Wk[tid * 4];
            *(float4*)&sWq[(tid >> 4) * 64 + (tid & 15) * 4] = wq4;
            *(float4*)&sWk[(tid >> 4) * 64 + (tid & 15) * 4] = wk4;
            if (tid < 64) { ssw[tid] = sw_[tid]; skb[tid] = kb[tid]; }
            int i2 = tid & 127;
            int r = i2 >> 2, c4 = (i2 & 3) * 4;
            if (tid < 128) {
                float4 aq = make_float4(0, 0, 0, 0);
                int n = n0 + r;
                if (n < N) aq = *(const float4*)&xq[(size_t)n * F + c4];
                sXq[r * 17 + c4] = aq.x; sXq[r * 17 + c4 + 1] = aq.y; sXq[r * 17 + c4 + 2] = aq.z; sXq[r * 17 + c4 + 3] = aq.w;
            } else {
                float4 ck = make_float4(0, 0, 0, 0);
                int m = m0 + r;
                if (m < N) ck = *(const float4*)&xk[(size_t)m * F + c4];
                sXk[r * 17 + c4] = ck.x; sXk[r * 17 + c4 + 1] = ck.y; sXk[r * 17 + c4 + 2] = ck.z; sXk[r * 17 + c4 + 3] = ck.w;
            }
        }
        __syncthreads();
        {
            int r = tid >> 3, o0 = (tid & 7) * 8;
            float xr[16], xkr[16];
#pragma unroll
            for (int f = 0; f < 16; f++) { xr[f] = sXq[r * 17 + f]; xkr[f] = sXk[r * 17 + f]; }
#pragma unroll
            for (int j = 0; j < 8; j++) {
                int o = o0 + j;
                float aq = 0.f, ak = skb[o];
#pragma unroll
                for (int f = 0; f < 16; f++) { aq += xr[f] * sWq[f * 64 + o]; ak += xkr[f] * sWk[f * 64 + o]; }
                sQ[r * 65 + o] = aq; sK[r * 65 + o] = ak;
            }
        }
        __syncthreads();
        float s00 = 0.f, s01 = 0.f, s10 = 0.f, s11 = 0.f;
#pragma unroll 2
        for (int d = 0; d < 64; d++) {
            float w = ssw[d];
            float q1 = sQ[ti * 65 + d], q2 = sQ[(ti + 16) * 65 + d];
            float k1 = sK[tj * 65 + d], k2 = sK[(tj + 16) * 65 + d];
            s00 += tanh_poly(q1 + k1) * w;
            s01 += tanh_poly(q1 + k2) * w;
            s10 += tanh_poly(q2 + k1) * w;
            s11 += tanh_poly(q2 + k2) * w;
        }
        int n1 = n0 + ti, n2 = n0 + ti + 16, m1 = m0 + tj, m2 = m0 + tj + 16;
        bool vn1 = n1 < N, vn2 = n2 < N, vm1 = m1 < N, vm2 = m2 < N;
        float e00 = (vn1 && vm1) ? __expf(s00) : 0.f;
        float e01 = (vn1 && vm2) ? __expf(s01) : 0.f;
        float e10 = (vn2 && vm1) ? __expf(s10) : 0.f;
        float e11 = (vn2 && vm2) ? __expf(s11) : 0.f;
        float part1 = e00 + e01, part2 = e10 + e11;
        for (int d = 8; d > 0; d >>= 1) {
            part1 += __shfl_down(part1, d, 16);
            part2 += __shfl_down(part2, d, 16);
        }
        if (tj == 0) {
            if (vn1) atomicAdd(&rsum[bt * N + n1], part1);
            if (vn2) atomicAdd(&rsum[bt * N + n2], part2);
        }
        __syncthreads();
        float* tile = sQ;  // 32x33
        tile[tj * 33 + ti] = e00;
        tile[(tj + 16) * 33 + ti] = e01;
        tile[tj * 33 + ti + 16] = e10;
        tile[(tj + 16) * 33 + ti + 16] = e11;
        __syncthreads();
        {
            int row = tid >> 3, c4 = (tid & 7) * 4;
            int m = m0 + row;
            if (m < N) {
                float4 v = make_float4(tile[row * 33 + c4], tile[row * 33 + c4 + 1],
                                       tile[row * 33 + c4 + 2], tile[row * 33 + c4 + 3]);
                *(float4*)&attnT[(size_t)bt * PS * PS + (size_t)m * PS + n0 + c4] = v;
            }
        }
    }
}

// ---------------- parameter block for the persistent kernel ----------------
struct KP {
    const float *inp, *adj;
    const float *Wsrc, *bsrc, *Wtgt, *btgt, *Wes, *bes, *Wet, *bet;
    const float *Wz, *bz, *Wr, *br, *Wc, *bc;
    const float *Ws, *bs, *Wsh, *bsh, *Wlong, *blong, *Wfus, *bfus;
    float *Ts, *A2, *sbuf, *tbuf, *P, *P2, *catg, *catc, *zb, *attnT, *x1, *xshort, *h, *target, *rsum;
    float *out;
    unsigned *cnt, *gen;
};

// ---------------- grid barrier (sense-reversing, device scope) ----------------
__device__ __forceinline__ void gbar(unsigned* cnt, unsigned* gen, unsigned nb) {
    __syncthreads();
    if (threadIdx.x == 0) {
        __threadfence();
        unsigned g = __hip_atomic_load(gen, __ATOMIC_RELAXED, __HIP_MEMORY_SCOPE_AGENT);
        unsigned arrived = __hip_atomic_fetch_add(cnt, 1u, __ATOMIC_ACQ_REL, __HIP_MEMORY_SCOPE_AGENT);
        if (arrived == nb - 1u) {
            __hip_atomic_store(cnt, 0u, __ATOMIC_RELAXED, __HIP_MEMORY_SCOPE_AGENT);
            __hip_atomic_store(gen, g + 1u, __ATOMIC_RELEASE, __HIP_MEMORY_SCOPE_AGENT);
        } else {
            int spins = 0;
            while (__hip_atomic_load(gen, __ATOMIC_ACQUIRE, __HIP_MEMORY_SCOPE_AGENT) == g) {
                if (++spins > (1 << 22)) break;  // bounded: broken barrier -> wrong answer, not hang
                __builtin_amdgcn_s_sleep(8);
            }
        }
        __threadfence();
    }
    __syncthreads();
}

// ---------------- cell stage A (lane-split): hyper chain + one projection per lane ----------------
__device__ void d_cell_a(float* smem, int x13, int b, int lane, const KP& a, int tsel) {
    int w0 = x13 * 16;
    int tid = threadIdx.x, ty = tid >> 4, tx = tid & 15;
    float (*sTs)[16][33] = (float (*)[16][33])(smem);
    float (*sA2)[16][33] = (float (*)[16][33])(smem + 1056);
    float (*sH)[32][64]  = (float (*)[32][64])(smem + 2112);
    float (*cat)[193]    = (float (*)[193])(smem + 6208);
    float (*sW)[16]      = (float (*)[16])(smem + 9296);
    float (*sX)[16]      = (float (*)[16])(smem + 12368);
    float (*sWe)[16]     = (float (*)[16])(smem + 12624);
    float au[4] = {0, 0, 0, 0}, aw[4] = {0, 0, 0, 0};
    const float* hb = a.h + b * N * H;
    const float* xp = (tsel >= 0) ? (a.inp + ((size_t)(b * T + tsel)) * NF) : (a.xshort + (size_t)b * NF);
    int pidx = tid & 127;
    int pr = pidx >> 3, pc4 = (pidx & 7) * 4;
    float4 t4;
    float4 h4[2];
    int hr[2], hc[2];
#pragma unroll
    for (int k = 0; k < 2; k++) { int l4 = tid + k * 256; hr[k] = l4 >> 4; hc[k] = (l4 & 15) * 4; }
    auto loadT = [&](int v0) {
        t4 = make_float4(0, 0, 0, 0);
        const float* src = (tid < 128) ? a.Ts : a.A2;
        int w = w0 + pr;
        if (w < N) t4 = *(const float4*)&src[(size_t)w * PS + v0 + pc4];
#pragma unroll
        for (int k = 0; k < 2; k++) {
            float4 hv = make_float4(0, 0, 0, 0);
            int v = v0 + hr[k];
            if (v < N) hv = *(const float4*)&hb[(size_t)v * H + hc[k]];
            h4[k] = hv;
        }
    };
    loadT(0);
    int cur = 0;
    for (int t = 0; t < 7; t++) {
        __syncthreads();
        {
            float (*dst)[33] = (tid < 128) ? sTs[cur] : sA2[cur];
            dst[pr][pc4] = t4.x; dst[pr][pc4 + 1] = t4.y; dst[pr][pc4 + 2] = t4.z; dst[pr][pc4 + 3] = t4.w;
        }
#pragma unroll
        for (int k = 0; k < 2; k++) *(float4*)&sH[cur][hr[k]][hc[k]] = h4[k];
        if (t < 6) loadT((t + 1) * 32);
        __syncthreads();
#pragma unroll 8
        for (int v = 0; v < 32; v++) {
            float pu = sTs[cur][ty][v], pw = sA2[cur][ty][v];
#pragma unroll
            for (int j = 0; j < 4; j++) {
                float x = sH[cur][v][tx * 4 + j];
                au[j] += pu * x; aw[j] += pw * x;
            }
        }
        cur ^= 1;
    }
    int w = w0 + ty;
    bool valid = w < N;
    __syncthreads();
    if (valid) {
#pragma unroll
        for (int j = 0; j < 4; j++) {
            int c = tx * 4 + j;
            float hv = hb[(size_t)w * H + c];
            float u = au[j], w2 = aw[j];
            cat[ty][c] = hv;
            cat[ty][64 + c] = ALPHA * hv + GAMMA * u;
            cat[ty][128 + c] = ALPHA * hv + ALPHA * GAMMA * u + GAMMA * GAMMA * w2;
        }
    } else {
#pragma unroll
        for (int j = 0; j < 4; j++) {
            int c = tx * 4 + j;
            cat[ty][c] = 0; cat[ty][64 + c] = 0; cat[ty][128 + c] = 0;
        }
    }
    const float* Wg = lane ? a.Wtgt : a.Wsrc;
    const float* bg = lane ? a.btgt : a.bsrc;
    const float* We = lane ? a.Wet : a.Wes;
    const float* be = lane ? a.bet : a.bes;
    {
        float4 wv[3];
#pragma unroll
        for (int k = 0; k < 3; k++) wv[k] = *(const float4*)&Wg[(tid + k * 256) * 4];
        float4 xv = make_float4(0, 0, 0, 0), ev = make_float4(0, 0, 0, 0);
        int sr = 0, sc = 0;
        if (tid < 64) {
            sr = tid >> 2; sc = (tid & 3) * 4;
            int n = w0 + sr;
            if (n < N) xv = *(const float4*)&xp[(size_t)n * F + sc];
            ev = *(const float4*)&We[tid * 4];
        }
#pragma unroll
        for (int k = 0; k < 3; k++) {
            int l4 = tid + k * 256;
            int r = l4 >> 2, c4 = (l4 & 3) * 4;
            *(float4*)&sW[r][c4] = wv[k];
        }
        if (tid < 64) {
            *(float4*)&sX[sr][sc] = xv;
            *(float4*)&sWe[sr][sc] = ev;
        }
    }
    __syncthreads();
    if (lane == 0 && valid) {
#pragma unroll
        for (int j = 0; j < 5; j++) {
            int c = tx * 5 + j;
            float v = (c < 16) ? sX[ty][c] : hb[(size_t)w * H + (c - 16)];
            a.catg[((size_t)(b * N + w)) * 80 + c] = v;
        }
    }
    {
        float ctx = bg[tx];
#pragma unroll 8
        for (int c = 0; c < 192; c++) ctx += cat[ty][c] * sW[c][tx];
        float xe = be[tx];
#pragma unroll
        for (int f = 0; f < 16; f++) xe += sX[ty][f] * sWe[f][tx];
        if (valid) {
            float val = tanh_fast(TA * xe * ctx);
            if (lane == 0) a.sbuf[(size_t)(b * N + w) * DH + tx] = val;
            else           a.tbuf[(size_t)(b * N + w) * DH + tx] = val;
        }
    }
}

// ---------------- cell stage B: adjacency rows + rowsum + direct P write (stride PS) ----------------
__device__ void d_cell_bP(float* smem, int x13, int b, const KP& a) {
    int v0 = x13 * 16;
    int tid = threadIdx.x, ty = tid >> 4, tx = tid & 15;
    float (*sS)[17] = (float (*)[17])(smem);
    float (*sT)[17] = (float (*)[17])(smem + 3519);
    for (int l4 = tid; l4 < 828; l4 += 256) {
        float4 sv = *(const float4*)&a.sbuf[(size_t)b * N * 16 + l4 * 4];
        float4 tv = *(const float4*)&a.tbuf[(size_t)b * N * 16 + l4 * 4];
        int r = l4 >> 2, c = (l4 & 3) * 4;
        sS[r][c] = sv.x; sS[r][c + 1] = sv.y; sS[r][c + 2] = sv.z; sS[r][c + 3] = sv.w;
        sT[r][c] = tv.x; sT[r][c + 1] = tv.y; sT[r][c + 2] = tv.z; sT[r][c + 3] = tv.w;
    }
    __syncthreads();
    int v = v0 + ty;
    bool valid = v < N;
    int vc = valid ? v : (N - 1);
    float sv[16], tv[16];
#pragma unroll
    for (int k = 0; k < 16; k++) { sv[k] = sS[vc][k]; tv[k] = sT[vc][k]; }
    float val[13];
    float rsum = 0.f;
#pragma unroll
    for (int idx = 0; idx < 13; idx++) {
        int w = tx + 16 * idx;
        float r = 0.f;
        if (w < N) {
            float acc = 0.f;
#pragma unroll
            for (int k = 0; k < 16; k++) acc += sv[k] * sT[w][k] - tv[k] * sS[w][k];
            r = tanh_fast(TA * acc);
            r = r > 0.f ? r : 0.f;
            if (w == v) r += 1.f;
        }
        val[idx] = r;
        rsum += r;
    }
    float tot = rsum;
    for (int d = 8; d > 0; d >>= 1) tot += __shfl_down(tot, d, 16);
    tot = __shfl(tot, 0, 16);
    float rinv = BETA / (tot + 1e-8f);
    if (valid) {
        float* Pb = a.P + (size_t)b * PS * PS;
#pragma unroll
        for (int idx = 0; idx < 13; idx++) {
            int w = tx + 16 * idx;
            if (w < N) Pb[(size_t)w * PS + v] = val[idx] * rinv + GAMMA * a.adj[v * N + w];
        }
    }
}

// ---------------- aux bodies (carved smem union) ----------------
__device__ __forceinline__ void body_prop_xr(float* smem, int w0, int bt,
    const float* __restrict__ attnT, const float* __restrict__ rsum,
    const float* __restrict__ Ts, const float* __restrict__ inp, float* __restrict__ x1)
{
    int b = bt >> 2, tau = bt & 3;
    const float* xb = inp + ((size_t)(b * T + 20 + tau)) * NF;
    const float* PA = attnT + (size_t)bt * PS * PS;
    int tid = threadIdx.x, ty = tid >> 4, tx = tid & 15;
    float (*sPA)[16][33] = (float(*)[16][33])(smem);
    float (*sPT)[16][33] = (float(*)[16][33])(smem + 1056);
    float (*sX)[32][17]  = (float(*)[32][17])(smem + 2112);
    float (*sXs)[32][17] = (float(*)[32][17])(smem + 3200);
    float accA = 0.f, accT = 0.f;
    int prr = tid >> 3, pcc = (tid & 7) * 4;
    int xrr = (tid - 128) >> 2, xcc = ((tid - 128) & 3) * 4;
    float4 pa, pt, xv;
    float rinv_;
    auto loadT = [&](int v0) {
        pa = make_float4(0, 0, 0, 0); pt = make_float4(0, 0, 0, 0); xv = make_float4(0, 0, 0, 0); rinv_ = 0.f;
        if (tid < 128) {
            int w = w0 + prr;
            if (w < N) {
                pa = *(const float4*)&PA[(size_t)w * PS + v0 + pcc];
                pt = *(const float4*)&Ts[(size_t)w * PS + v0 + pcc];
            }
        } else {
            int v = v0 + xrr;
            if (v < N) {
                xv = *(const float4*)&xb[(size_t)v * F + xcc];
                rinv_ = __builtin_amdgcn_rcpf(rsum[bt * N + v]);
            }
        }
    };
    loadT(0);
    int cur = 0;
    for (int t = 0; t < 7; t++) {
        __syncthreads();
        if (tid < 128) {
            sPA[cur][prr][pcc] = pa.x; sPA[cur][prr][pcc + 1] = pa.y; sPA[cur][prr][pcc + 2] = pa.z; sPA[cur][prr][pcc + 3] = pa.w;
            sPT[cur][prr][pcc] = pt.x; sPT[cur][prr][pcc + 1] = pt.y; sPT[cur][prr][pcc + 2] = pt.z; sPT[cur][prr][pcc + 3] = pt.w;
        } else {
            sX[cur][xrr][xcc] = xv.x; sX[cur][xrr][xcc + 1] = xv.y; sX[cur][xrr][xcc + 2] = xv.z; sX[cur][xrr][xcc + 3] = xv.w;
            sXs[cur][xrr][xcc] = xv.x * rinv_; sXs[cur][xrr][xcc + 1] = xv.y * rinv_;
            sXs[cur][xrr][xcc + 2] = xv.z * rinv_; sXs[cur][xrr][xcc + 3] = xv.w * rinv_;
        }
        if (t < 6) loadT((t + 1) * 32);
        __syncthreads();
#pragma unroll 8
        for (int v = 0; v < 32; v++) {
            accA += sPA[cur][ty][v] * sXs[cur][v][tx];
            accT += sPT[cur][ty][v] * sX[cur][v][tx];
        }
        cur ^= 1;
    }
    int w = w0 + ty;
    if (w < N) x1[((size_t)(bt * N + w)) * 16 + tx] = ALPHA * xb[w * F + tx] + GAMMA * (accA + accT);
}

__device__ __forceinline__ void body_sgc2(float* smem, int w0, int bt,
    const float* __restrict__ attnT, const float* __restrict__ rsum,
    const float* __restrict__ Ts, const float* __restrict__ x1, const float* __restrict__ inp,
    const float* __restrict__ Ws, const float* __restrict__ bs, float* __restrict__ target)
{
    int b = bt >> 2, tau = bt & 3;
    const float* xb = inp + ((size_t)(b * T + 20 + tau)) * NF;
    const float* PA = attnT + (size_t)bt * PS * PS;
    int tid = threadIdx.x, ty = tid >> 4, tx = tid & 15;
    float (*sPA)[16][33] = (float(*)[16][33])(smem);
    float (*sPT)[16][33] = (float(*)[16][33])(smem + 1056);
    float (*sX)[32][17]  = (float(*)[32][17])(smem + 2112);
    float (*sXs)[32][17] = (float(*)[32][17])(smem + 3200);
    float (*scat)[48]    = (float(*)[48])(smem + 4288);
    float (*sWs)[64]     = (float(*)[64])(smem + 5056);
    float accA = 0.f, accT = 0.f;
    int prr = tid >> 3, pcc = (tid & 7) * 4;
    int xrr = (tid - 128) >> 2, xcc = ((tid - 128) & 3) * 4;
    float4 pa, pt, xv;
    float rinv_;
    auto loadT = [&](int v0) {
        pa = make_float4(0, 0, 0, 0); pt = make_float4(0, 0, 0, 0); xv = make_float4(0, 0, 0, 0); rinv_ = 0.f;
        if (tid < 128) {
            int w = w0 + prr;
            if (w < N) {
                pa = *(const float4*)&PA[(size_t)w * PS + v0 + pcc];
                pt = *(const float4*)&Ts[(size_t)w * PS + v0 + pcc];
            }
        } else {
            int v = v0 + xrr;
            if (v < N) {
                xv = *(const float4*)&x1[((size_t)(bt * N + v)) * 16 + xcc];
                rinv_ = __builtin_amdgcn_rcpf(rsum[bt * N + v]);
            }
        }
    };
    loadT(0);
    int cur = 0;
    for (int t = 0; t < 7; t++) {
        __syncthreads();
        if (tid < 128) {
            sPA[cur][prr][pcc] = pa.x; sPA[cur][prr][pcc + 1] = pa.y; sPA[cur][prr][pcc + 2] = pa.z; sPA[cur][prr][pcc + 3] = pa.w;
            sPT[cur][prr][pcc] = pt.x; sPT[cur][prr][pcc + 1] = pt.y; sPT[cur][prr][pcc + 2] = pt.z; sPT[cur][prr][pcc + 3] = pt.w;
        } else {
            sX[cur][xrr][xcc] = xv.x; sX[cur][xrr][xcc + 1] = xv.y; sX[cur][xrr][xcc + 2] = xv.z; sX[cur][xrr][xcc + 3] = xv.w;
            sXs[cur][xrr][xcc] = xv.x * rinv_; sXs[cur][xrr][xcc + 1] = xv.y * rinv_;
            sXs[cur][xrr][xcc + 2] = xv.z * rinv_; sXs[cur][xrr][xcc + 3] = xv.w * rinv_;
        }
        if (t < 6) loadT((t + 1) * 32);
        __syncthreads();
#pragma unroll 8
        for (int v = 0; v < 32; v++) {
            accA += sPA[cur][ty][v] * sXs[cur][v][tx];
            accT += sPT[cur][ty][v] * sX[cur][v][tx];
        }
        cur ^= 1;
    }
    int w = w0 + ty;
    bool valid = w < N;
    __syncthreads();
    for (int l = tid; l < 512; l += 256) {
        int i = l >> 5, c = l & 31;
        int ww = w0 + i;
        float vv = 0;
        if (ww < N) {
            if (c < 16) vv = xb[ww * F + c];
            else vv = x1[((size_t)bt * N + ww) * 16 + (c - 16)];
        }
        scat[i][c] = vv;
    }
    {
        float x0 = valid ? xb[w * F + tx] : 0.f;
        scat[ty][32 + tx] = ALPHA * x0 + GAMMA * (accA + accT);
    }
    {
        float4 wv[3];
#pragma unroll
        for (int k = 0; k < 3; k++) wv[k] = *(const float4*)&Ws[(tid + k * 256) * 4];
#pragma unroll
        for (int k = 0; k < 3; k++) {
            int l4 = tid + k * 256;
            *(float4*)&sWs[l4 >> 4][(l4 & 15) * 4] = wv[k];
        }
    }
    __syncthreads();
    float acc[4];
#pragma unroll
    for (int j = 0; j < 4; j++) acc[j] = bs[tx * 4 + j];
#pragma unroll 8
    for (int cc = 0; cc < 48; cc++) {
        float cv = scat[ty][cc];
        float4 w4 = *(const float4*)&sWs[cc][tx * 4];
        acc[0] += cv * w4.x; acc[1] += cv * w4.y; acc[2] += cv * w4.z; acc[3] += cv * w4.w;
    }
    if (valid) {
#pragma unroll
        for (int j = 0; j < 4; j++) {
            float r = acc[j] > 0.f ? acc[j] : 0.f;
            atomicAdd(&target[(b * N + w) * 64 + tx * 4 + j], r);
        }
    }
}

__device__ __forceinline__ void body_short(float* smem, int n0, int b,
    const float* __restrict__ target, const float* __restrict__ Wsh, const float* __restrict__ bsh,
    float* __restrict__ out, float* __restrict__ xshort)
{
    int tid = threadIdx.x, ty = tid >> 4, tx = tid & 15;
    float (*trow)[65] = (float(*)[65])(smem);
    float (*sW)[16]   = (float(*)[16])(smem + 1040);
    {
        int r = tid >> 4, c4 = (tid & 15) * 4;
        int n = n0 + r;
        float4 tv = make_float4(0, 0, 0, 0);
        if (n < N) tv = *(const float4*)&target[((size_t)(b * N + n)) * 64 + c4];
        trow[r][c4] = tv.x; trow[r][c4 + 1] = tv.y; trow[r][c4 + 2] = tv.z; trow[r][c4 + 3] = tv.w;
        float4 wv = *(const float4*)&Wsh[tid * 4];
        *(float4*)&sW[tid >> 2][(tid & 3) * 4] = wv;
    }
    __syncthreads();
    float acc = bsh[tx];
#pragma unroll 8
    for (int o = 0; o < 64; o++) acc += trow[ty][o] * sW[o][tx];
    int n = n0 + ty;
    if (n < N) {
        out[((size_t)0 * B * N + b * N + n) * 16 + tx] = acc;
        xshort[(b * N + n) * 16 + tx] = acc;
    }
}

// ---------------- P^2 tile ----------------
__device__ void d_psq(float* smem, int tile, const KP& a) {
    int b = tile / 169, r = tile % 169;
    int w0 = (r % 13) * 16, v0 = (r / 13) * 16;
    const float* Pb = a.P + (size_t)b * PS * PS;
    float (*sA)[16][33] = (float (*)[16][33])(smem);
    float (*sB)[32][17] = (float (*)[32][17])(smem + 1056);
    int tid = threadIdx.x, ty = tid >> 4, tx = tid & 15;
    int ar = tid >> 4, ac = (tid & 15) * 2;
    int br = tid >> 3, bc = (tid & 7) * 2;
    float2 av, bv;
    auto loadT = [&](int u0) {
        av = make_float2(0, 0); bv = make_float2(0, 0);
        int w = w0 + ar;
        if (w < N) av = *(const float2*)&Pb[(size_t)w * PS + u0 + ac];
        int u = u0 + br;
        if (u < N) bv = *(const float2*)&Pb[(size_t)u * PS + v0 + bc];
    };
    loadT(0);
    int cur = 0;
    float acc = 0.f;
    for (int t = 0; t < 7; t++) {
        __syncthreads();
        sA[cur][ar][ac] = av.x; sA[cur][ar][ac + 1] = av.y;
        sB[cur][br][bc] = bv.x; sB[cur][br][bc + 1] = bv.y;
        if (t < 6) loadT((t + 1) * 32);
        __syncthreads();
#pragma unroll 8
        for (int u = 0; u < 32; u++) acc += sA[cur][ty][u] * sB[cur][u][tx];
        cur ^= 1;
    }
    int w = w0 + ty, v = v0 + tx;
    if (w < N && v < N) a.P2[(size_t)b * PS * PS + (size_t)w * PS + v] = acc;
}

// ---------------- gate: dual-prop (P, P^2) phase A + GEMM ----------------
__device__ void d_gate2(float* smem, int x13, int b, int mode, const KP& a, int tsel) {
    const float* W    = (mode == 0) ? a.Wz : (mode == 1) ? a.Wr : a.Wc;
    const float* bias = (mode == 0) ? a.bz : (mode == 1) ? a.br : a.bc;
    const float* catv = (mode < 2) ? a.catg : a.catc;
    int w0 = x13 * 16;
    int tid = threadIdx.x, ty = tid >> 4, tx = tid & 15;
    const float* Pb = a.P + (size_t)b * PS * PS;
    const float* Qb = a.P2 + (size_t)b * PS * PS;
    float (*sC)[241]  = (float (*)[241])(smem);
    float (*sP)[33]   = (float (*)[33])(smem + 3856);
    float (*sQ)[33]   = (float (*)[33])(smem + 4384);
    float (*sX)[81]   = (float (*)[81])(smem + 4912);
    float (*sW)[65]   = (float (*)[65])(smem + 7504);
    float (*hrow)[65] = (float (*)[65])(smem + 10624);
    float (*trow)[65] = (float (*)[65])(smem + 11664);
    // load g0 (80 cols)
    for (int l4 = tid; l4 < 320; l4 += 256) {
        int r = l4 / 20, c4 = (l4 % 20) * 4;
        int w = w0 + r;
        float4 v4 = make_float4(0, 0, 0, 0);
        if (w < N) v4 = *(const float4*)&catv[((size_t)(b * N + w)) * 80 + c4];
        sC[r][c4] = v4.x; sC[r][c4 + 1] = v4.y; sC[r][c4 + 2] = v4.z; sC[r][c4 + 3] = v4.w;
    }
    // phase A: dual prop over g0 -> g1 = a*g0 + P g0 ; g2 = a*g0 + a*(P g0) + P^2 g0
    float accP[5] = {0, 0, 0, 0, 0}, accQ[5] = {0, 0, 0, 0, 0};
    int prr = tid >> 4, prc = (tid & 15) * 2;
    int xrow = tid & 31, xc0 = (tid >> 5) * 10;
    float2 pv, qv;
    float2 xv[5];
    auto loadT = [&](int v0) {
        pv = make_float2(0, 0); qv = make_float2(0, 0);
        int w = w0 + prr;
        if (w < N) {
            pv = *(const float2*)&Pb[(size_t)w * PS + v0 + prc];
            qv = *(const float2*)&Qb[(size_t)w * PS + v0 + prc];
        }
        int v = v0 + xrow;
#pragma unroll
        for (int k = 0; k < 5; k++) xv[k] = make_float2(0, 0);
        if (v < N) {
            const float* src = &catv[((size_t)(b * N + v)) * 80 + xc0];
#pragma unroll
            for (int k = 0; k < 5; k++) xv[k] = *(const float2*)&src[k * 2];
        }
    };
    loadT(0);
    for (int t = 0; t < 7; t++) {
        __syncthreads();
        sP[prr][prc] = pv.x; sP[prr][prc + 1] = pv.y;
        sQ[prr][prc] = qv.x; sQ[prr][prc + 1] = qv.y;
#pragma unroll
        for (int k = 0; k < 5; k++) { sX[xrow][xc0 + 2 * k] = xv[k].x; sX[xrow][xc0 + 2 * k + 1] = xv[k].y; }
        if (t < 6) loadT((t + 1) * 32);
        __syncthreads();
#pragma unroll 8
        for (int v = 0; v < 32; v++) {
            float p = sP[ty][v], q = sQ[ty][v];
#pragma unroll
            for (int j = 0; j < 5; j++) {
                float x = sX[v][tx * 5 + j];
                accP[j] += p * x;
                accQ[j] += q * x;
            }
        }
    }
#pragma unroll
    for (int j = 0; j < 5; j++) {
        int c = tx * 5 + j;
        float g0 = sC[ty][c];
        sC[ty][80 + c]  = ALPHA * g0 + accP[j];
        sC[ty][160 + c] = ALPHA * g0 + ALPHA * accP[j] + accQ[j];
    }
    // phase B: GEMM over 240 cols with register prefetch
    float4 wv[3];
#pragma unroll
    for (int k = 0; k < 3; k++) wv[k] = *(const float4*)&W[(tid + k * 256) * 4];
    float ga[4];
#pragma unroll
    for (int j = 0; j < 4; j++) ga[j] = bias[tx * 4 + j];
    for (int ch = 0; ch < 5; ch++) {
        __syncthreads();
#pragma unroll
        for (int k = 0; k < 3; k++) {
            int l4 = tid + k * 256;
            int r = l4 >> 4, cc = (l4 & 15) * 4;
            sW[r][cc] = wv[k].x; sW[r][cc + 1] = wv[k].y; sW[r][cc + 2] = wv[k].z; sW[r][cc + 3] = wv[k].w;
        }
        if (ch < 4) {
#pragma unroll
            for (int k = 0; k < 3; k++) wv[k] = *(const float4*)&W[(size_t)(ch + 1) * 3072 + (tid + k * 256) * 4];
        }
        __syncthreads();
        int c0 = ch * 48;
#pragma unroll 8
        for (int cc = 0; cc < 48; cc++) {
            float cv = sC[ty][c0 + cc];
#pragma unroll
            for (int j = 0; j < 4; j++) ga[j] += cv * sW[cc][tx * 4 + j];
        }
    }
    int w = w0 + ty;
    bool valid = w < N;
    if (mode == 0) {
        if (valid) {
#pragma unroll
            for (int j = 0; j < 4; j++) a.zb[((size_t)(b * N + w)) * 64 + tx * 4 + j] = sigm(ga[j]);
        }
    } else if (mode == 1) {
        if (valid) {
#pragma unroll
            for (int j = 0; j < 4; j++) {
                int o = tx * 4 + j;
                a.catc[((size_t)(b * N + w)) * 80 + 16 + o] = sigm(ga[j]) * a.h[((size_t)(b * N + w)) * 64 + o];
            }
            if (tx < 4) {
                const float* xp = (tsel >= 0) ? (a.inp + ((size_t)(b * T + tsel)) * NF) : (a.xshort + (size_t)b * NF);
#pragma unroll
                for (int j = 0; j < 4; j++) {
                    int c = tx * 4 + j;
                    a.catc[((size_t)(b * N + w)) * 80 + c] = xp[w * F + c];
                }
            }
        }
    } else {
#pragma unroll
        for (int j = 0; j < 4; j++) {
            int o = tx * 4 + j;
            float cval = tanh_fast(ga[j]);
            float zv = 0.f, hv = 0.f;
            if (valid) { zv = a.zb[((size_t)(b * N + w)) * 64 + o]; hv = a.h[((size_t)(b * N + w)) * 64 + o]; }
            float hn = zv * hv + (1.f - zv) * cval;
            if (valid) a.h[((size_t)(b * N + w)) * 64 + o] = hn;
            hrow[ty][o] = valid ? hn : 0.f;
        }
        if (mode == 3) {
            for (int l = tid; l < 1024; l += 256) {
                int i = l >> 6, o = l & 63;
                int ww = w0 + i;
                trow[i][o] = (ww < N) ? a.target[((size_t)(b * N + ww)) * 64 + o] : 0.f;
            }
            __syncthreads();
            float lg = a.blong[tx];
            float fs = a.bfus[tx];
#pragma unroll 8
            for (int o = 0; o < 64; o++) {
                lg += hrow[ty][o] * a.Wlong[o * 16 + tx];
                fs += trow[ty][o] * a.Wfus[o * 16 + tx] + hrow[ty][o] * a.Wfus[(64 + o) * 16 + tx];
            }
            if (valid) {
                a.out[((size_t)1 * B * N + b * N + w) * 16 + tx] = lg;
                a.out[((size_t)2 * B * N + b * N + w) * 16 + tx] = fs;
            }
        }
    }
}

// ---------------- persistent kernel: 6 cells, 30 grid barriers, 1 launch ----------------
// __launch_bounds__(256, 2): 2 blocks/CU guaranteed by regalloc (<=256 VGPR, spill if needed).
// LDS 51.7KB*2 = 103KB <= 160KB. Grid 512 = 2/CU * 256CU -> all blocks co-resident.
__global__ __launch_bounds__(256, 2) void k_cells(KP a) {
    __shared__ __align__(16) float smem[12928];
    const unsigned nb = gridDim.x;
    for (int cell = 0; cell < 6; cell++) {
        int tsel = (cell < 5) ? cell * 4 : -1;
        // phase 1: cell_a (208 tiles)
        for (int t = blockIdx.x; t < 208; t += nb) { __syncthreads(); d_cell_a(smem, t % 13, (t / 13) & 7, t / 104, a, tsel); }
        gbar(a.cnt, a.gen, nb);
        // phase 2: cell_bP (104 tiles)
        for (int t = blockIdx.x; t < 104; t += nb) { __syncthreads(); d_cell_bP(smem, t % 13, t / 13, a); }
        gbar(a.cnt, a.gen, nb);
        // phase 3: P^2 (1352 tiles) + aux tail rides cells 0/1/2
        int aux = (cell == 0) ? 1 : (cell == 1) ? 2 : (cell == 2) ? 3 : 0;
        int ntil = 1352 + ((aux == 1 || aux == 2) ? 416 : (aux == 3) ? 104 : 0);
        for (int t = blockIdx.x; t < ntil; t += nb) {
            __syncthreads();
            if (t < 1352) d_psq(smem, t, a);
            else {
                int idx = t - 1352;
                if (aux == 1)      body_prop_xr(smem, (idx % 13) * 16, idx / 13, a.attnT, a.rsum, a.Ts, a.inp, a.x1);
                else if (aux == 2) body_sgc2(smem, (idx % 13) * 16, idx / 13, a.attnT, a.rsum, a.Ts, a.x1, a.inp, a.Ws, a.bs, a.target);
                else               body_short(smem, (idx % 13) * 16, idx / 13, a.target, a.Wsh, a.bsh, a.out, a.xshort);
            }
        }
        gbar(a.cnt, a.gen, nb);
        // phase 4: z/r gates (208 tiles: mode = t/104)
        for (int t = blockIdx.x; t < 208; t += nb) { __syncthreads(); d_gate2(smem, t % 13, (t / 13) & 7, t / 104, a, tsel); }
        gbar(a.cnt, a.gen, nb);
        // phase 5: c gate + h update (+ heads on final cell)
        for (int t = blockIdx.x; t < 104; t += nb) { __syncthreads(); d_gate2(smem, t % 13, t / 13, (cell == 5) ? 3 : 2, a, tsel); }
        gbar(a.cnt, a.gen, nb);
    }
}

extern "C" void kernel_launch(void* const* d_in, const int* in_sizes, int n_in,
                              void* d_out, int out_size, void* d_ws, size_t ws_size,
                              hipStream_t stream) {
    const float* inp = (const float*)d_in[0];
    const float* adj = (const float*)d_in[1];
    const float* src_gen_w = (const float*)d_in[2];
    const float* src_gen_b = (const float*)d_in[3];
    const float* tgt_gen_w = (const float*)d_in[4];
    const float* tgt_gen_b = (const float*)d_in[5];
    const float* src_emb_w = (const float*)d_in[6];
    const float* src_emb_b = (const float*)d_in[7];
    const float* tgt_emb_w = (const float*)d_in[8];
    const float* tgt_emb_b = (const float*)d_in[9];
    const float* gru_z_w = (const float*)d_in[10];
    const float* gru_z_b = (const float*)d_in[11];
    const float* gru_r_w = (const float*)d_in[12];
    const float* gru_r_b = (const float*)d_in[13];
    const float* gru_c_w = (const float*)d_in[14];
    const float* gru_c_b = (const float*)d_in[15];
    const float* attn_q_w = (const float*)d_in[16];
    const float* attn_k_w = (const float*)d_in[17];
    const float* attn_k_b = (const float*)d_in[18];
    const float* attn_s_w = (const float*)d_in[19];
    const float* sgcn_w = (const float*)d_in[20];
    const float* sgcn_b = (const float*)d_in[21];
    const float* short_w = (const float*)d_in[22];
    const float* short_b = (const float*)d_in[23];
    const float* long_w = (const float*)d_in[24];
    const float* long_b = (const float*)d_in[25];
    const float* fus_w = (const float*)d_in[26];
    const float* fus_b = (const float*)d_in[27];
    float* out = (float*)d_out;

    float* ws = (float*)d_ws;
    size_t off = 0;
    auto A = [&](size_t n) { n = (n + 3) & ~(size_t)3; float* p = ws + off; off += n; return p; };
    float* Ts = A((size_t)PS * PS);
    float* A2 = A((size_t)PS * PS);
    float* sbuf = A((size_t)B * N * DH);
    float* tbuf = A((size_t)B * N * DH);
    float* P = A((size_t)B * PS * PS);
    float* P2 = A((size_t)B * PS * PS);
    float* catg = A((size_t)B * N * 80);
    float* catc = A((size_t)B * N * 80);
    float* zb = A((size_t)B * N * 64);
    float* attnT = A((size_t)32 * PS * PS);
    float* x1 = A((size_t)32 * NF);
    float* xshort = A(BNF);
    size_t zero_begin = off;
    float* h = A((size_t)B * N * H);
    float* target = A((size_t)B * N * 64);
    float* rsum = A((size_t)32 * N);
    float* barf = A(4);
    size_t zero_end = off;
    (void)ws_size; (void)in_sizes; (void)n_in; (void)out_size;

    hipMemsetAsync(h, 0, (zero_end - zero_begin) * sizeof(float), stream);
    k_stage0<<<1785, 256, 0, stream>>>(adj, inp, attn_q_w, attn_k_w, attn_k_b, attn_s_w, Ts, A2, attnT, rsum);

    KP kp;
    kp.inp = inp; kp.adj = adj;
    kp.Wsrc = src_gen_w; kp.bsrc = src_gen_b; kp.Wtgt = tgt_gen_w; kp.btgt = tgt_gen_b;
    kp.Wes = src_emb_w; kp.bes = src_emb_b; kp.Wet = tgt_emb_w; kp.bet = tgt_emb_b;
    kp.Wz = gru_z_w; kp.bz = gru_z_b; kp.Wr = gru_r_w; kp.br = gru_r_b; kp.Wc = gru_c_w; kp.bc = gru_c_b;
    kp.Ws = sgcn_w; kp.bs = sgcn_b; kp.Wsh = short_w; kp.bsh = short_b;
    kp.Wlong = long_w; kp.blong = long_b; kp.Wfus = fus_w; kp.bfus = fus_b;
    kp.Ts = Ts; kp.A2 = A2; kp.sbuf = sbuf; kp.tbuf = tbuf; kp.P = P; kp.P2 = P2;
    kp.catg = catg; kp.catc = catc; kp.zb = zb; kp.attnT = attnT; kp.x1 = x1; kp.xshort = xshort;
    kp.h = h; kp.target = target; kp.rsum = rsum; kp.out = out;
    kp.cnt = (unsigned*)barf; kp.gen = ((unsigned*)barf) + 1;

    k_cells<<<512, 256, 0, stream>>>(kp);
}

// Round 4
// 606.522 us; speedup vs baseline: 9.2019x; 9.2019x over previous
//
#include <hip/hip_runtime.h>

// PSGIN forward on MI355X. fp32 I/O. Multi-kernel pipeline.
// R11 (630us): stage0 merge. R12 FAILED: prop1 grid shrink (latency regime: parallelism wins).
// R13 (628us): poly tanh. R14 (630us, NEUTRAL): P^2 algebra + aux absorption.
// Fit: T = 9us/link * links + 0.068us/MFLOP * work — ~270us is per-link fixed cost.
// R15/R16 FAILED: persistent kernel 5581us — device-scope barrier fences writeback+invalidate
// per-XCD L2 (FETCH 250MB vs 15MB working set), every post-barrier load pays ~900cy HBM latency
// at 8 waves/CU. Persistent direction structurally dead on 8-XCD gfx950.
// R17: revert to R14 + (a) cell0 cell_a fused into stage0 (h=0 -> ctx=bias, trivial GEMM;
// -1 serial link), (b) cell_bP 8-row tiles (26xB grid, per-thread path halved).

constexpr int B = 8, T = 24, N = 207, F = 16, H = 64, DH = 16;
constexpr int PS = 208; // padded stride for N x N matrices
constexpr float ALPHA = 0.05f, BETA = 0.95f, GAMMA = 0.95f, TA = 2.0f;
constexpr int NF = N * F;      // 3312
constexpr int BNF = B * N * F; // 26496

__device__ __forceinline__ float tanh_fast(float x) { float e = __expf(2.f * x); return 1.f - 2.f / (e + 1.f); }
__device__ __forceinline__ float sigm(float x) { return 1.f / (1.f + __expf(-x)); }
// cubic/quintic series tanh: x*(1 + x2*(-1/3 + (2/15)x2)); |err|<1e-3 for |x|<0.6.
__device__ __forceinline__ float tanh_poly(float x) {
    float x2 = x * x;
    float c = __builtin_fmaf(x2, 0.13333333f, -0.33333333f);
    return x * __builtin_fmaf(x2, c, 1.f);
}

// =============== stage 0: Ts transpose + A2 = (adj@adj)^T + attention scores + cell0 s,t ===============
// grid x: [0,49) A2; [49,217) Ts; [217,1785) attn 32x32 tiles; [1785,1889) cell0 cell_a (h=0)
__global__ __launch_bounds__(256) void k_stage0(
    const float* __restrict__ adj, const float* __restrict__ inp,
    const float* __restrict__ Wq, const float* __restrict__ Wk,
    const float* __restrict__ kb, const float* __restrict__ sw_,
    const float* __restrict__ Wes, const float* __restrict__ bes,
    const float* __restrict__ Wet, const float* __restrict__ bet,
    const float* __restrict__ bsrc, const float* __restrict__ btgt,
    float* __restrict__ Ts, float* __restrict__ A2,
    float* __restrict__ attnT, float* __restrict__ rsum,
    float* __restrict__ s_out, float* __restrict__ t_out, float* __restrict__ catg)
{
    __shared__ __align__(16) float smem[7424];
    int bid = blockIdx.x, tid = threadIdx.x;
    if (bid < 49) {
        int vb = (bid % 7) * 32, wb = (bid / 7) * 32;
        float* sA = smem;          // [32][33]
        float* sB = smem + 1056;   // [32][33]
        float acc[4] = {0, 0, 0, 0};
        int i0 = tid >> 5, j = tid & 31;
        for (int u0 = 0; u0 < N; u0 += 32) {
            __syncthreads();
            for (int l = tid; l < 1024; l += 256) {
                int i = l >> 5, jj = l & 31;
                int v = vb + i, u = u0 + jj;
                sA[i * 33 + jj] = (v < N && u < N) ? adj[v * N + u] : 0.f;
                int uu = u0 + i, w = wb + jj;
                sB[i * 33 + jj] = (uu < N && w < N) ? adj[uu * N + w] : 0.f;
            }
            __syncthreads();
#pragma unroll 8
            for (int u = 0; u < 32; u++) {
                float bv = sB[u * 33 + j];
#pragma unroll
                for (int k = 0; k < 4; k++) acc[k] += sA[(i0 + k * 8) * 33 + u] * bv;
            }
        }
#pragma unroll
        for (int k = 0; k < 4; k++) {
            int v = vb + i0 + k * 8, w = wb + j;
            if (v < N && w < N) A2[(size_t)w * PS + v] = acc[k];
        }
    } else if (bid < 217) {
        int i = (bid - 49) * 256 + tid;
        if (i < N * N) {
            int w = i / N, v = i % N;
            Ts[(size_t)w * PS + v] = adj[v * N + w];
        }
    } else if (bid < 1785) {
        int idx = bid - 217;
        int bt = idx / 49, rem = idx % 49;
        int n0 = (rem % 7) * 32, m0 = (rem / 7) * 32;
        int b = bt >> 2, tau = bt & 3;
        int ti = tid >> 4, tj = tid & 15;
        float* sQ = smem;            // 32*65
        float* sK = smem + 2080;     // 32*65
        float* sWq = smem + 4160;    // 16*64
        float* sWk = smem + 5184;    // 16*64
        float* sXq = smem + 6208;    // 32*17
        float* sXk = smem + 6752;    // 32*17
        float* ssw = smem + 7296;    // 64
        float* skb = smem + 7360;    // 64
        const float* xq = inp + ((size_t)(b * T + (T - 1))) * NF;
        const float* xk = inp + ((size_t)(b * T + 20 + tau)) * NF;
        {
            float4 wq4 = *(const float4*)&Wq[tid * 4];
            float4 wk4 = *(const float4*)&Wk[tid * 4];
            *(float4*)&sWq[(tid >> 4) * 64 + (tid & 15) * 4] = wq4;
            *(float4*)&sWk[(tid >> 4) * 64 + (tid & 15) * 4] = wk4;
            if (tid < 64) { ssw[tid] = sw_[tid]; skb[tid] = kb[tid]; }
            int i2 = tid & 127;
            int r = i2 >> 2, c4 = (i2 & 3) * 4;
            if (tid < 128) {
                float4 aq = make_float4(0, 0, 0, 0);
                int n = n0 + r;
                if (n < N) aq = *(const float4*)&xq[(size_t)n * F + c4];
                sXq[r * 17 + c4] = aq.x; sXq[r * 17 + c4 + 1] = aq.y; sXq[r * 17 + c4 + 2] = aq.z; sXq[r * 17 + c4 + 3] = aq.w;
            } else {
                float4 ck = make_float4(0, 0, 0, 0);
                int m = m0 + r;
                if (m < N) ck = *(const float4*)&xk[(size_t)m * F + c4];
                sXk[r * 17 + c4] = ck.x; sXk[r * 17 + c4 + 1] = ck.y; sXk[r * 17 + c4 + 2] = ck.z; sXk[r * 17 + c4 + 3] = ck.w;
            }
        }
        __syncthreads();
        {
            int r = tid >> 3, o0 = (tid & 7) * 8;
            float xr[16], xkr[16];
#pragma unroll
            for (int f = 0; f < 16; f++) { xr[f] = sXq[r * 17 + f]; xkr[f] = sXk[r * 17 + f]; }
#pragma unroll
            for (int j = 0; j < 8; j++) {
                int o = o0 + j;
                float aq = 0.f, ak = skb[o];
#pragma unroll
                for (int f = 0; f < 16; f++) { aq += xr[f] * sWq[f * 64 + o]; ak += xkr[f] * sWk[f * 64 + o]; }
                sQ[r * 65 + o] = aq; sK[r * 65 + o] = ak;
            }
        }
        __syncthreads();
        float s00 = 0.f, s01 = 0.f, s10 = 0.f, s11 = 0.f;
#pragma unroll 2
        for (int d = 0; d < 64; d++) {
            float w = ssw[d];
            float q1 = sQ[ti * 65 + d], q2 = sQ[(ti + 16) * 65 + d];
            float k1 = sK[tj * 65 + d], k2 = sK[(tj + 16) * 65 + d];
            s00 += tanh_poly(q1 + k1) * w;
            s01 += tanh_poly(q1 + k2) * w;
            s10 += tanh_poly(q2 + k1) * w;
            s11 += tanh_poly(q2 + k2) * w;
        }
        int n1 = n0 + ti, n2 = n0 + ti + 16, m1 = m0 + tj, m2 = m0 + tj + 16;
        bool vn1 = n1 < N, vn2 = n2 < N, vm1 = m1 < N, vm2 = m2 < N;
        float e00 = (vn1 && vm1) ? __expf(s00) : 0.f;
        float e01 = (vn1 && vm2) ? __expf(s01) : 0.f;
        float e10 = (vn2 && vm1) ? __expf(s10) : 0.f;
        float e11 = (vn2 && vm2) ? __expf(s11) : 0.f;
        float part1 = e00 + e01, part2 = e10 + e11;
        for (int d = 8; d > 0; d >>= 1) {
            part1 += __shfl_down(part1, d, 16);
            part2 += __shfl_down(part2, d, 16);
        }
        if (tj == 0) {
            if (vn1) atomicAdd(&rsum[bt * N + n1], part1);
            if (vn2) atomicAdd(&rsum[bt * N + n2], part2);
        }
        __syncthreads();
        float* tile = sQ;  // 32x33
        tile[tj * 33 + ti] = e00;
        tile[(tj + 16) * 33 + ti] = e01;
        tile[tj * 33 + ti + 16] = e10;
        tile[(tj + 16) * 33 + ti + 16] = e11;
        __syncthreads();
        {
            int row = tid >> 3, c4 = (tid & 7) * 4;
            int m = m0 + row;
            if (m < N) {
                float4 v = make_float4(tile[row * 33 + c4], tile[row * 33 + c4 + 1],
                                       tile[row * 33 + c4 + 2], tile[row * 33 + c4 + 3]);
                *(float4*)&attnT[(size_t)bt * PS * PS + (size_t)m * PS + n0 + c4] = v;
            }
        }
    } else {
        // cell0 cell_a, h = 0: ctx = bias; s = tanh(TA*(x@Wes+bes)*bsrc), t likewise.
        int idx = bid - 1785;
        int x13 = idx % 13, b = idx / 13;
        int w0 = x13 * 16;
        int ty = tid >> 4, tx = tid & 15;
        float* sX  = smem;        // [16][17]
        float* sWs = smem + 272;  // [16][16]
        float* sWt = smem + 528;  // [16][16]
        const float* xp = inp + ((size_t)(b * T + 0)) * NF;
        {
            int w = w0 + ty;
            sX[ty * 17 + tx] = (w < N) ? xp[(size_t)w * F + tx] : 0.f;
            sWs[ty * 16 + tx] = Wes[ty * 16 + tx];
            sWt[ty * 16 + tx] = Wet[ty * 16 + tx];
        }
        __syncthreads();
        float xs = bes[tx], xt = bet[tx];
#pragma unroll
        for (int f = 0; f < 16; f++) {
            float xv = sX[ty * 17 + f];
            xs += xv * sWs[f * 16 + tx];
            xt += xv * sWt[f * 16 + tx];
        }
        int w = w0 + ty;
        if (w < N) {
            s_out[((size_t)(b * N + w)) * DH + tx] = tanh_fast(TA * xs * bsrc[tx]);
            t_out[((size_t)(b * N + w)) * DH + tx] = tanh_fast(TA * xt * btgt[tx]);
            // catg for cell0: [x | h=0]
            catg[((size_t)(b * N + w)) * 80 + tx] = sX[ty * 17 + tx];
#pragma unroll
            for (int j = 0; j < 4; j++) catg[((size_t)(b * N + w)) * 80 + 16 + tx * 4 + j] = 0.f;
        }
    }
}

// ---------------- cell stage A (lane-split): hyper chain + one projection per lane ----------------
__global__ __launch_bounds__(256) void k_cell_a(
    const float* __restrict__ h, const float* __restrict__ Ts, const float* __restrict__ A2,
    const float* __restrict__ xseq, int tsel, const float* __restrict__ xbuf,
    const float* __restrict__ Wsrc, const float* __restrict__ bsrc,
    const float* __restrict__ Wtgt, const float* __restrict__ btgt,
    const float* __restrict__ Wes, const float* __restrict__ bes,
    const float* __restrict__ Wet, const float* __restrict__ bet,
    float* __restrict__ s_out, float* __restrict__ t_out, float* __restrict__ catg) {
    int b = blockIdx.y, w0 = blockIdx.x * 16, lane = blockIdx.z;
    int tid = threadIdx.x, ty = tid >> 4, tx = tid & 15;
    __shared__ float sTs[2][16][33], sA2[2][16][33];
    __shared__ float sH[2][32][64];
    __shared__ float cat[16][193];
    __shared__ float sW[192][16];
    __shared__ float sX[16][16], sWe[16][16];
    float au[4] = {0, 0, 0, 0}, aw[4] = {0, 0, 0, 0};
    const float* hb = h + b * N * H;
    const float* xp = (tsel >= 0) ? (xseq + ((size_t)(b * T + tsel)) * NF) : (xbuf + (size_t)b * NF);
    int pidx = tid & 127;
    int pr = pidx >> 3, pc4 = (pidx & 7) * 4;
    float4 t4;
    float4 h4[2];
    int hr[2], hc[2];
#pragma unroll
    for (int k = 0; k < 2; k++) { int l4 = tid + k * 256; hr[k] = l4 >> 4; hc[k] = (l4 & 15) * 4; }
    auto loadT = [&](int v0) {
        t4 = make_float4(0, 0, 0, 0);
        const float* src = (tid < 128) ? Ts : A2;
        int w = w0 + pr;
        if (w < N) t4 = *(const float4*)&src[(size_t)w * PS + v0 + pc4];
#pragma unroll
        for (int k = 0; k < 2; k++) {
            float4 hv = make_float4(0, 0, 0, 0);
            int v = v0 + hr[k];
            if (v < N) hv = *(const float4*)&hb[(size_t)v * H + hc[k]];
            h4[k] = hv;
        }
    };
    loadT(0);
    int cur = 0;
    for (int t = 0; t < 7; t++) {
        __syncthreads();
        {
            float (*dst)[33] = (tid < 128) ? sTs[cur] : sA2[cur];
            dst[pr][pc4] = t4.x; dst[pr][pc4 + 1] = t4.y; dst[pr][pc4 + 2] = t4.z; dst[pr][pc4 + 3] = t4.w;
        }
#pragma unroll
        for (int k = 0; k < 2; k++) *(float4*)&sH[cur][hr[k]][hc[k]] = h4[k];
        if (t < 6) loadT((t + 1) * 32);
        __syncthreads();
#pragma unroll 8
        for (int v = 0; v < 32; v++) {
            float pu = sTs[cur][ty][v], pw = sA2[cur][ty][v];
#pragma unroll
            for (int j = 0; j < 4; j++) {
                float x = sH[cur][v][tx * 4 + j];
                au[j] += pu * x; aw[j] += pw * x;
            }
        }
        cur ^= 1;
    }
    int w = w0 + ty;
    bool valid = w < N;
    __syncthreads();
    if (valid) {
#pragma unroll
        for (int j = 0; j < 4; j++) {
            int c = tx * 4 + j;
            float hv = hb[(size_t)w * H + c];
            float u = au[j], w2 = aw[j];
            cat[ty][c] = hv;
            cat[ty][64 + c] = ALPHA * hv + GAMMA * u;
            cat[ty][128 + c] = ALPHA * hv + ALPHA * GAMMA * u + GAMMA * GAMMA * w2;
        }
    } else {
#pragma unroll
        for (int j = 0; j < 4; j++) {
            int c = tx * 4 + j;
            cat[ty][c] = 0; cat[ty][64 + c] = 0; cat[ty][128 + c] = 0;
        }
    }
    const float* Wg = lane ? Wtgt : Wsrc;
    const float* bg = lane ? btgt : bsrc;
    const float* We = lane ? Wet : Wes;
    const float* be = lane ? bet : bes;
    {
        float4 wv[3];
#pragma unroll
        for (int k = 0; k < 3; k++) wv[k] = *(const float4*)&Wg[(tid + k * 256) * 4];
        float4 xv = make_float4(0, 0, 0, 0), ev = make_float4(0, 0, 0, 0);
        int sr = 0, sc = 0;
        if (tid < 64) {
            sr = tid >> 2; sc = (tid & 3) * 4;
            int n = w0 + sr;
            if (n < N) xv = *(const float4*)&xp[(size_t)n * F + sc];
            ev = *(const float4*)&We[tid * 4];
        }
#pragma unroll
        for (int k = 0; k < 3; k++) {
            int l4 = tid + k * 256;
            int r = l4 >> 2, c4 = (l4 & 3) * 4;
            *(float4*)&sW[r][c4] = wv[k];
        }
        if (tid < 64) {
            *(float4*)&sX[sr][sc] = xv;
            *(float4*)&sWe[sr][sc] = ev;
        }
    }
    __syncthreads();
    if (lane == 0 && valid) {
#pragma unroll
        for (int j = 0; j < 5; j++) {
            int c = tx * 5 + j;
            float v = (c < 16) ? sX[ty][c] : hb[(size_t)w * H + (c - 16)];
            catg[((size_t)(b * N + w)) * 80 + c] = v;
        }
    }
    {
        float ctx = bg[tx];
#pragma unroll 8
        for (int c = 0; c < 192; c++) ctx += cat[ty][c] * sW[c][tx];
        float xe = be[tx];
#pragma unroll
        for (int f = 0; f < 16; f++) xe += sX[ty][f] * sWe[f][tx];
        if (valid) {
            float val = tanh_fast(TA * xe * ctx);
            if (lane == 0) s_out[(size_t)(b * N + w) * DH + tx] = val;
            else           t_out[(size_t)(b * N + w) * DH + tx] = val;
        }
    }
}

// ---------------- cell stage B: 8-row v-tiles (R17: halved per-thread path), grid (26, B) ----------------
__global__ __launch_bounds__(256) void k_cell_bP(const float* __restrict__ s_in, const float* __restrict__ t_in,
                                                 const float* __restrict__ adj, float* __restrict__ P) {
    int b = blockIdx.y, v0 = blockIdx.x * 8;
    int tid = threadIdx.x, ty = tid >> 5, tx = tid & 31;
    __shared__ float sS[N][17], sT[N][17];
    for (int l4 = tid; l4 < 828; l4 += 256) {
        float4 sv = *(const float4*)&s_in[(size_t)b * N * 16 + l4 * 4];
        float4 tv = *(const float4*)&t_in[(size_t)b * N * 16 + l4 * 4];
        int r = l4 >> 2, c = (l4 & 3) * 4;
        sS[r][c] = sv.x; sS[r][c + 1] = sv.y; sS[r][c + 2] = sv.z; sS[r][c + 3] = sv.w;
        sT[r][c] = tv.x; sT[r][c + 1] = tv.y; sT[r][c + 2] = tv.z; sT[r][c + 3] = tv.w;
    }
    __syncthreads();
    int v = v0 + ty;
    bool valid = v < N;
    int vc = valid ? v : (N - 1);
    float sv[16], tv[16];
#pragma unroll
    for (int k = 0; k < 16; k++) { sv[k] = sS[vc][k]; tv[k] = sT[vc][k]; }
    float val[7];
    float rsum = 0.f;
#pragma unroll
    for (int idx = 0; idx < 7; idx++) {
        int w = tx + 32 * idx;
        float r = 0.f;
        if (w < N) {
            float a = 0.f;
#pragma unroll
            for (int k = 0; k < 16; k++) a += sv[k] * sT[w][k] - tv[k] * sS[w][k];
            r = tanh_fast(TA * a);
            r = r > 0.f ? r : 0.f;
            if (w == v) r += 1.f;
        }
        val[idx] = r;
        rsum += r;
    }
    float tot = rsum;
    for (int d = 16; d > 0; d >>= 1) tot += __shfl_down(tot, d, 32);
    tot = __shfl(tot, 0, 32);
    float rinv = BETA / (tot + 1e-8f);
    if (valid) {
        float* Pb = P + (size_t)b * PS * PS;
#pragma unroll
        for (int idx = 0; idx < 7; idx++) {
            int w = tx + 32 * idx;
            if (w < N) Pb[(size_t)w * PS + v] = val[idx] * rinv + GAMMA * adj[v * N + w];
        }
    }
}

// ---------------- aux bodies (fused into k_psq launches; carved smem union) ----------------
__device__ __forceinline__ void body_prop_xr(float* smem, int w0, int bt,
    const float* __restrict__ attnT, const float* __restrict__ rsum,
    const float* __restrict__ Ts, const float* __restrict__ inp, float* __restrict__ x1)
{
    int b = bt >> 2, tau = bt & 3;
    const float* xb = inp + ((size_t)(b * T + 20 + tau)) * NF;
    const float* PA = attnT + (size_t)bt * PS * PS;
    int tid = threadIdx.x, ty = tid >> 4, tx = tid & 15;
    float (*sPA)[16][33] = (float(*)[16][33])(smem);
    float (*sPT)[16][33] = (float(*)[16][33])(smem + 1056);
    float (*sX)[32][17]  = (float(*)[32][17])(smem + 2112);
    float (*sXs)[32][17] = (float(*)[32][17])(smem + 3200);
    float accA = 0.f, accT = 0.f;
    int prr = tid >> 3, pcc = (tid & 7) * 4;
    int xrr = (tid - 128) >> 2, xcc = ((tid - 128) & 3) * 4;
    float4 pa, pt, xv;
    float rinv_;
    auto loadT = [&](int v0) {
        pa = make_float4(0, 0, 0, 0); pt = make_float4(0, 0, 0, 0); xv = make_float4(0, 0, 0, 0); rinv_ = 0.f;
        if (tid < 128) {
            int w = w0 + prr;
            if (w < N) {
                pa = *(const float4*)&PA[(size_t)w * PS + v0 + pcc];
                pt = *(const float4*)&Ts[(size_t)w * PS + v0 + pcc];
            }
        } else {
            int v = v0 + xrr;
            if (v < N) {
                xv = *(const float4*)&xb[(size_t)v * F + xcc];
                rinv_ = __builtin_amdgcn_rcpf(rsum[bt * N + v]);
            }
        }
    };
    loadT(0);
    int cur = 0;
    for (int t = 0; t < 7; t++) {
        __syncthreads();
        if (tid < 128) {
            sPA[cur][prr][pcc] = pa.x; sPA[cur][prr][pcc + 1] = pa.y; sPA[cur][prr][pcc + 2] = pa.z; sPA[cur][prr][pcc + 3] = pa.w;
            sPT[cur][prr][pcc] = pt.x; sPT[cur][prr][pcc + 1] = pt.y; sPT[cur][prr][pcc + 2] = pt.z; sPT[cur][prr][pcc + 3] = pt.w;
        } else {
            sX[cur][xrr][xcc] = xv.x; sX[cur][xrr][xcc + 1] = xv.y; sX[cur][xrr][xcc + 2] = xv.z; sX[cur][xrr][xcc + 3] = xv.w;
            sXs[cur][xrr][xcc] = xv.x * rinv_; sXs[cur][xrr][xcc + 1] = xv.y * rinv_;
            sXs[cur][xrr][xcc + 2] = xv.z * rinv_; sXs[cur][xrr][xcc + 3] = xv.w * rinv_;
        }
        if (t < 6) loadT((t + 1) * 32);
        __syncthreads();
#pragma unroll 8
        for (int v = 0; v < 32; v++) {
            accA += sPA[cur][ty][v] * sXs[cur][v][tx];
            accT += sPT[cur][ty][v] * sX[cur][v][tx];
        }
        cur ^= 1;
    }
    int w = w0 + ty;
    if (w < N) x1[((size_t)(bt * N + w)) * 16 + tx] = ALPHA * xb[w * F + tx] + GAMMA * (accA + accT);
}

__device__ __forceinline__ void body_sgc2(float* smem, int w0, int bt,
    const float* __restrict__ attnT, const float* __restrict__ rsum,
    const float* __restrict__ Ts, const float* __restrict__ x1, const float* __restrict__ inp,
    const float* __restrict__ Ws, const float* __restrict__ bs, float* __restrict__ target)
{
    int b = bt >> 2, tau = bt & 3;
    const float* xb = inp + ((size_t)(b * T + 20 + tau)) * NF;
    const float* PA = attnT + (size_t)bt * PS * PS;
    int tid = threadIdx.x, ty = tid >> 4, tx = tid & 15;
    float (*sPA)[16][33] = (float(*)[16][33])(smem);
    float (*sPT)[16][33] = (float(*)[16][33])(smem + 1056);
    float (*sX)[32][17]  = (float(*)[32][17])(smem + 2112);
    float (*sXs)[32][17] = (float(*)[32][17])(smem + 3200);
    float (*scat)[48]    = (float(*)[48])(smem + 4288);
    float (*sWs)[64]     = (float(*)[64])(smem + 5056);
    float accA = 0.f, accT = 0.f;
    int prr = tid >> 3, pcc = (tid & 7) * 4;
    int xrr = (tid - 128) >> 2, xcc = ((tid - 128) & 3) * 4;
    float4 pa, pt, xv;
    float rinv_;
    auto loadT = [&](int v0) {
        pa = make_float4(0, 0, 0, 0); pt = make_float4(0, 0, 0, 0); xv = make_float4(0, 0, 0, 0); rinv_ = 0.f;
        if (tid < 128) {
            int w = w0 + prr;
            if (w < N) {
                pa = *(const float4*)&PA[(size_t)w * PS + v0 + pcc];
                pt = *(const float4*)&Ts[(size_t)w * PS + v0 + pcc];
            }
        } else {
            int v = v0 + xrr;
            if (v < N) {
                xv = *(const float4*)&x1[((size_t)(bt * N + v)) * 16 + xcc];
                rinv_ = __builtin_amdgcn_rcpf(rsum[bt * N + v]);
            }
        }
    };
    loadT(0);
    int cur = 0;
    for (int t = 0; t < 7; t++) {
        __syncthreads();
        if (tid < 128) {
            sPA[cur][prr][pcc] = pa.x; sPA[cur][prr][pcc + 1] = pa.y; sPA[cur][prr][pcc + 2] = pa.z; sPA[cur][prr][pcc + 3] = pa.w;
            sPT[cur][prr][pcc] = pt.x; sPT[cur][prr][pcc + 1] = pt.y; sPT[cur][prr][pcc + 2] = pt.z; sPT[cur][prr][pcc + 3] = pt.w;
        } else {
            sX[cur][xrr][xcc] = xv.x; sX[cur][xrr][xcc + 1] = xv.y; sX[cur][xrr][xcc + 2] = xv.z; sX[cur][xrr][xcc + 3] = xv.w;
            sXs[cur][xrr][xcc] = xv.x * rinv_; sXs[cur][xrr][xcc + 1] = xv.y * rinv_;
            sXs[cur][xrr][xcc + 2] = xv.z * rinv_; sXs[cur][xrr][xcc + 3] = xv.w * rinv_;
        }
        if (t < 6) loadT((t + 1) * 32);
        __syncthreads();
#pragma unroll 8
        for (int v = 0; v < 32; v++) {
            accA += sPA[cur][ty][v] * sXs[cur][v][tx];
            accT += sPT[cur][ty][v] * sX[cur][v][tx];
        }
        cur ^= 1;
    }
    int w = w0 + ty;
    bool valid = w < N;
    __syncthreads();
    for (int l = tid; l < 512; l += 256) {
        int i = l >> 5, c = l & 31;
        int ww = w0 + i;
        float vv = 0;
        if (ww < N) {
            if (c < 16) vv = xb[ww * F + c];
            else vv = x1[((size_t)bt * N + ww) * 16 + (c - 16)];
        }
        scat[i][c] = vv;
    }
    {
        float x0 = valid ? xb[w * F + tx] : 0.f;
        scat[ty][32 + tx] = ALPHA * x0 + GAMMA * (accA + accT);
    }
    {
        float4 wv[3];
#pragma unroll
        for (int k = 0; k < 3; k++) wv[k] = *(const float4*)&Ws[(tid + k * 256) * 4];
#pragma unroll
        for (int k = 0; k < 3; k++) {
            int l4 = tid + k * 256;
            *(float4*)&sWs[l4 >> 4][(l4 & 15) * 4] = wv[k];
        }
    }
    __syncthreads();
    float acc[4];
#pragma unroll
    for (int j = 0; j < 4; j++) acc[j] = bs[tx * 4 + j];
#pragma unroll 8
    for (int cc = 0; cc < 48; cc++) {
        float cv = scat[ty][cc];
        float4 w4 = *(const float4*)&sWs[cc][tx * 4];
        acc[0] += cv * w4.x; acc[1] += cv * w4.y; acc[2] += cv * w4.z; acc[3] += cv * w4.w;
    }
    if (valid) {
#pragma unroll
        for (int j = 0; j < 4; j++) {
            float r = acc[j] > 0.f ? acc[j] : 0.f;
            atomicAdd(&target[(b * N + w) * 64 + tx * 4 + j], r);
        }
    }
}

__device__ __forceinline__ void body_short(float* smem, int n0, int b,
    const float* __restrict__ target, const float* __restrict__ Wsh, const float* __restrict__ bsh,
    float* __restrict__ out, float* __restrict__ xshort)
{
    int tid = threadIdx.x, ty = tid >> 4, tx = tid & 15;
    float (*trow)[65] = (float(*)[65])(smem);
    float (*sW)[16]   = (float(*)[16])(smem + 1040);
    {
        int r = tid >> 4, c4 = (tid & 15) * 4;
        int n = n0 + r;
        float4 tv = make_float4(0, 0, 0, 0);
        if (n < N) tv = *(const float4*)&target[((size_t)(b * N + n)) * 64 + c4];
        trow[r][c4] = tv.x; trow[r][c4 + 1] = tv.y; trow[r][c4 + 2] = tv.z; trow[r][c4 + 3] = tv.w;
        float4 wv = *(const float4*)&Wsh[tid * 4];
        *(float4*)&sW[tid >> 2][(tid & 3) * 4] = wv;
    }
    __syncthreads();
    float acc = bsh[tx];
#pragma unroll 8
    for (int o = 0; o < 64; o++) acc += trow[ty][o] * sW[o][tx];
    int n = n0 + ty;
    if (n < N) {
        out[((size_t)0 * B * N + b * N + n) * 16 + tx] = acc;
        xshort[(b * N + n) * 16 + tx] = acc;
    }
}

// ---------------- P^2 per cell (+ fused aux blocks) ----------------
// grid x: [0,1352) = P2 16x16 tiles (169 per batch); [1352, ...) = aux job (prop_xr / sgc2 / short)
__global__ __launch_bounds__(256) void k_psq(
    const float* __restrict__ P, float* __restrict__ P2, int aux,
    const float* __restrict__ attnT, const float* __restrict__ rsum,
    const float* __restrict__ Ts, const float* __restrict__ inp, float* __restrict__ x1,
    const float* __restrict__ Ws, const float* __restrict__ bs, float* __restrict__ target,
    const float* __restrict__ Wsh, const float* __restrict__ bsh,
    float* __restrict__ out, float* __restrict__ xshort)
{
    __shared__ __align__(16) float smem[8128];
    int bid = blockIdx.x, tid = threadIdx.x;
    if (bid < 1352) {
        int b = bid / 169, r = bid % 169;
        int w0 = (r % 13) * 16, v0 = (r / 13) * 16;
        const float* Pb = P + (size_t)b * PS * PS;
        float (*sA)[16][33] = (float(*)[16][33])(smem);
        float (*sB)[32][17] = (float(*)[32][17])(smem + 1056);
        int ty = tid >> 4, tx = tid & 15;
        int ar = tid >> 4, ac = (tid & 15) * 2;
        int br = tid >> 3, bc = (tid & 7) * 2;
        float2 av, bv;
        auto loadT = [&](int u0) {
            av = make_float2(0, 0); bv = make_float2(0, 0);
            int w = w0 + ar;
            if (w < N) av = *(const float2*)&Pb[(size_t)w * PS + u0 + ac];
            int u = u0 + br;
            if (u < N) bv = *(const float2*)&Pb[(size_t)u * PS + v0 + bc];
        };
        loadT(0);
        int cur = 0;
        float acc = 0.f;
        for (int t = 0; t < 7; t++) {
            __syncthreads();
            sA[cur][ar][ac] = av.x; sA[cur][ar][ac + 1] = av.y;
            sB[cur][br][bc] = bv.x; sB[cur][br][bc + 1] = bv.y;
            if (t < 6) loadT((t + 1) * 32);
            __syncthreads();
#pragma unroll 8
            for (int u = 0; u < 32; u++) acc += sA[cur][ty][u] * sB[cur][u][tx];
            cur ^= 1;
        }
        int w = w0 + ty, v = v0 + tx;
        if (w < N && v < N) P2[(size_t)b * PS * PS + (size_t)w * PS + v] = acc;
    } else {
        int idx = bid - 1352;
        if (aux == 1)      body_prop_xr(smem, (idx % 13) * 16, idx / 13, attnT, rsum, Ts, inp, x1);
        else if (aux == 2) body_sgc2(smem, (idx % 13) * 16, idx / 13, attnT, rsum, Ts, x1, inp, Ws, bs, target);
        else               body_short(smem, (idx % 13) * 16, idx / 13, target, Wsh, bsh, out, xshort);
    }
}

// ---------------- gate: dual-prop (P, P^2) phase A + GEMM; replaces prop1+gate pair ----------------
__global__ __launch_bounds__(256) void k_gate2(
    const float* __restrict__ cat, const float* __restrict__ P, const float* __restrict__ P2,
    const float* __restrict__ Wa, const float* __restrict__ ba,
    const float* __restrict__ Wb, const float* __restrict__ bb,
    int baseMode,
    const float* __restrict__ xseq, int tsel, const float* __restrict__ xbuf,
    float* __restrict__ zbuf, float* __restrict__ ricat,
    float* __restrict__ h,
    const float* __restrict__ target,
    const float* __restrict__ Wlong, const float* __restrict__ blong,
    const float* __restrict__ Wfus, const float* __restrict__ bfus,
    float* __restrict__ out) {
    int mode = baseMode + blockIdx.z;
    const float* W = (mode == 1) ? Wb : Wa;
    const float* bias = (mode == 1) ? bb : ba;
    int b = blockIdx.y, w0 = blockIdx.x * 16;
    int tid = threadIdx.x, ty = tid >> 4, tx = tid & 15;
    const float* Pb = P + (size_t)b * PS * PS;
    const float* Qb = P2 + (size_t)b * PS * PS;
    __shared__ float sC[16][241];
    __shared__ float sP[16][33], sQ[16][33];
    __shared__ float sX[32][81];
    __shared__ float sW[48][65];
    __shared__ float hrow[16][65], trow[16][65];
    // load g0 (80 cols)
    for (int l4 = tid; l4 < 320; l4 += 256) {
        int r = l4 / 20, c4 = (l4 % 20) * 4;
        int w = w0 + r;
        float4 v4 = make_float4(0, 0, 0, 0);
        if (w < N) v4 = *(const float4*)&cat[((size_t)(b * N + w)) * 80 + c4];
        sC[r][c4] = v4.x; sC[r][c4 + 1] = v4.y; sC[r][c4 + 2] = v4.z; sC[r][c4 + 3] = v4.w;
    }
    // phase A: dual prop over g0 -> g1 = a*g0 + P g0 ; g2 = a*g0 + a*(P g0) + P^2 g0
    float accP[5] = {0, 0, 0, 0, 0}, accQ[5] = {0, 0, 0, 0, 0};
    int prr = tid >> 4, prc = (tid & 15) * 2;
    int xrow = tid & 31, xc0 = (tid >> 5) * 10;
    float2 pv, qv;
    float2 xv[5];
    auto loadT = [&](int v0) {
        pv = make_float2(0, 0); qv = make_float2(0, 0);
        int w = w0 + prr;
        if (w < N) {
            pv = *(const float2*)&Pb[(size_t)w * PS + v0 + prc];
            qv = *(const float2*)&Qb[(size_t)w * PS + v0 + prc];
        }
        int v = v0 + xrow;
#pragma unroll
        for (int k = 0; k < 5; k++) xv[k] = make_float2(0, 0);
        if (v < N) {
            const float* src = &cat[((size_t)(b * N + v)) * 80 + xc0];
#pragma unroll
            for (int k = 0; k < 5; k++) xv[k] = *(const float2*)&src[k * 2];
        }
    };
    loadT(0);
    for (int t = 0; t < 7; t++) {
        __syncthreads();
        sP[prr][prc] = pv.x; sP[prr][prc + 1] = pv.y;
        sQ[prr][prc] = qv.x; sQ[prr][prc + 1] = qv.y;
#pragma unroll
        for (int k = 0; k < 5; k++) { sX[xrow][xc0 + 2 * k] = xv[k].x; sX[xrow][xc0 + 2 * k + 1] = xv[k].y; }
        if (t < 6) loadT((t + 1) * 32);
        __syncthreads();
#pragma unroll 8
        for (int v = 0; v < 32; v++) {
            float p = sP[ty][v], q = sQ[ty][v];
#pragma unroll
            for (int j = 0; j < 5; j++) {
                float x = sX[v][tx * 5 + j];
                accP[j] += p * x;
                accQ[j] += q * x;
            }
        }
    }
#pragma unroll
    for (int j = 0; j < 5; j++) {
        int c = tx * 5 + j;
        float g0 = sC[ty][c];
        sC[ty][80 + c]  = ALPHA * g0 + accP[j];
        sC[ty][160 + c] = ALPHA * g0 + ALPHA * accP[j] + accQ[j];
    }
    // phase B: GEMM over 240 cols with register prefetch
    float4 wv[3];
#pragma unroll
    for (int k = 0; k < 3; k++) wv[k] = *(const float4*)&W[(tid + k * 256) * 4];
    float ga[4];
#pragma unroll
    for (int j = 0; j < 4; j++) ga[j] = bias[tx * 4 + j];
    for (int ch = 0; ch < 5; ch++) {
        __syncthreads();
#pragma unroll
        for (int k = 0; k < 3; k++) {
            int l4 = tid + k * 256;
            int r = l4 >> 4, cc = (l4 & 15) * 4;
            sW[r][cc] = wv[k].x; sW[r][cc + 1] = wv[k].y; sW[r][cc + 2] = wv[k].z; sW[r][cc + 3] = wv[k].w;
        }
        if (ch < 4) {
#pragma unroll
            for (int k = 0; k < 3; k++) wv[k] = *(const float4*)&W[(size_t)(ch + 1) * 3072 + (tid + k * 256) * 4];
        }
        __syncthreads();
        int c0 = ch * 48;
#pragma unroll 8
        for (int cc = 0; cc < 48; cc++) {
            float cv = sC[ty][c0 + cc];
#pragma unroll
            for (int j = 0; j < 4; j++) ga[j] += cv * sW[cc][tx * 4 + j];
        }
    }
    int w = w0 + ty;
    bool valid = w < N;
    if (mode == 0) {
        if (valid) {
#pragma unroll
            for (int j = 0; j < 4; j++) zbuf[((size_t)(b * N + w)) * 64 + tx * 4 + j] = sigm(ga[j]);
        }
    } else if (mode == 1) {
        if (valid) {
#pragma unroll
            for (int j = 0; j < 4; j++) {
                int o = tx * 4 + j;
                ricat[((size_t)(b * N + w)) * 80 + 16 + o] = sigm(ga[j]) * h[((size_t)(b * N + w)) * 64 + o];
            }
            if (tx < 4) {
                const float* xp = (tsel >= 0) ? (xseq + ((size_t)(b * T + tsel)) * NF) : (xbuf + (size_t)b * NF);
#pragma unroll
                for (int j = 0; j < 4; j++) {
                    int c = tx * 4 + j;
                    ricat[((size_t)(b * N + w)) * 80 + c] = xp[w * F + c];
                }
            }
        }
    } else {
#pragma unroll
        for (int j = 0; j < 4; j++) {
            int o = tx * 4 + j;
            float cval = tanh_fast(ga[j]);
            float zv = 0.f, hv = 0.f;
            if (valid) { zv = zbuf[((size_t)(b * N + w)) * 64 + o]; hv = h[((size_t)(b * N + w)) * 64 + o]; }
            float hn = zv * hv + (1.f - zv) * cval;
            if (valid) h[((size_t)(b * N + w)) * 64 + o] = hn;
            hrow[ty][o] = valid ? hn : 0.f;
        }
        if (mode == 3) {
            for (int l = tid; l < 1024; l += 256) {
                int i = l >> 6, o = l & 63;
                int ww = w0 + i;
                trow[i][o] = (ww < N) ? target[((size_t)(b * N + ww)) * 64 + o] : 0.f;
            }
            __syncthreads();
            float lg = blong[tx];
            float fs = bfus[tx];
#pragma unroll 8
            for (int o = 0; o < 64; o++) {
                lg += hrow[ty][o] * Wlong[o * 16 + tx];
                fs += trow[ty][o] * Wfus[o * 16 + tx] + hrow[ty][o] * Wfus[(64 + o) * 16 + tx];
            }
            if (valid) {
                out[((size_t)1 * B * N + b * N + w) * 16 + tx] = lg;
                out[((size_t)2 * B * N + b * N + w) * 16 + tx] = fs;
            }
        }
    }
}

extern "C" void kernel_launch(void* const* d_in, const int* in_sizes, int n_in,
                              void* d_out, int out_size, void* d_ws, size_t ws_size,
                              hipStream_t stream) {
    const float* inp = (const float*)d_in[0];
    const float* adj = (const float*)d_in[1];
    const float* src_gen_w = (const float*)d_in[2];
    const float* src_gen_b = (const float*)d_in[3];
    const float* tgt_gen_w = (const float*)d_in[4];
    const float* tgt_gen_b = (const float*)d_in[5];
    const float* src_emb_w = (const float*)d_in[6];
    const float* src_emb_b = (const float*)d_in[7];
    const float* tgt_emb_w = (const float*)d_in[8];
    const float* tgt_emb_b = (const float*)d_in[9];
    const float* gru_z_w = (const float*)d_in[10];
    const float* gru_z_b = (const float*)d_in[11];
    const float* gru_r_w = (const float*)d_in[12];
    const float* gru_r_b = (const float*)d_in[13];
    const float* gru_c_w = (const float*)d_in[14];
    const float* gru_c_b = (const float*)d_in[15];
    const float* attn_q_w = (const float*)d_in[16];
    const float* attn_k_w = (const float*)d_in[17];
    const float* attn_k_b = (const float*)d_in[18];
    const float* attn_s_w = (const float*)d_in[19];
    const float* sgcn_w = (const float*)d_in[20];
    const float* sgcn_b = (const float*)d_in[21];
    const float* short_w = (const float*)d_in[22];
    const float* short_b = (const float*)d_in[23];
    const float* long_w = (const float*)d_in[24];
    const float* long_b = (const float*)d_in[25];
    const float* fus_w = (const float*)d_in[26];
    const float* fus_b = (const float*)d_in[27];
    float* out = (float*)d_out;

    float* ws = (float*)d_ws;
    size_t off = 0;
    auto A = [&](size_t n) { n = (n + 3) & ~(size_t)3; float* p = ws + off; off += n; return p; };
    float* Ts = A((size_t)PS * PS);
    float* A2 = A((size_t)PS * PS);
    float* sbuf = A((size_t)B * N * DH);
    float* tbuf = A((size_t)B * N * DH);
    float* P = A((size_t)B * PS * PS);
    float* P2 = A((size_t)B * PS * PS);
    float* catg = A((size_t)B * N * 80);
    float* catc = A((size_t)B * N * 80);
    float* zb = A((size_t)B * N * 64);
    float* attnT = A((size_t)32 * PS * PS);
    float* x1 = A((size_t)32 * NF);
    float* xshort = A(BNF);
    size_t zero_begin = off;
    float* h = A((size_t)B * N * H);
    float* target = A((size_t)B * N * 64);
    float* rsum = A((size_t)32 * N);
    size_t zero_end = off;
    (void)ws_size; (void)in_sizes; (void)n_in; (void)out_size;

    hipMemsetAsync(h, 0, (zero_end - zero_begin) * sizeof(float), stream);
    // stage0 + cell0 cell_a fused (blocks 1785..1889)
    k_stage0<<<1889, 256, 0, stream>>>(adj, inp, attn_q_w, attn_k_w, attn_k_b, attn_s_w,
                                       src_emb_w, src_emb_b, tgt_emb_w, tgt_emb_b,
                                       src_gen_b, tgt_gen_b,
                                       Ts, A2, attnT, rsum, sbuf, tbuf, catg);

    auto run_cell = [&](int tsel, const float* xbuf, int finalFlag, int aux, bool skipA) {
        if (!skipA)
            k_cell_a<<<dim3(13, B, 2), 256, 0, stream>>>(h, Ts, A2, inp, tsel, xbuf,
                                                         src_gen_w, src_gen_b, tgt_gen_w, tgt_gen_b,
                                                         src_emb_w, src_emb_b, tgt_emb_w, tgt_emb_b, sbuf, tbuf, catg);
        k_cell_bP<<<dim3(26, B), 256, 0, stream>>>(sbuf, tbuf, adj, P);
        int extra = (aux == 1 || aux == 2) ? 416 : (aux == 3 ? 104 : 0);
        k_psq<<<1352 + extra, 256, 0, stream>>>(P, P2, aux, attnT, rsum, Ts, inp, x1,
                                                sgcn_w, sgcn_b, target, short_w, short_b, out, xshort);
        k_gate2<<<dim3(13, B, 2), 256, 0, stream>>>(catg, P, P2, gru_z_w, gru_z_b, gru_r_w, gru_r_b, 0,
                                                    inp, tsel, xbuf, zb, catc, h,
                                                    nullptr, nullptr, nullptr, nullptr, nullptr, nullptr);
        k_gate2<<<dim3(13, B, 1), 256, 0, stream>>>(catc, P, P2, gru_c_w, gru_c_b, nullptr, nullptr, 2 + finalFlag,
                                                    nullptr, 0, nullptr, zb, nullptr, h,
                                                    target, long_w, long_b, fus_w, fus_b, out);
    };

    run_cell(0, nullptr, 0, 1, true);    // cell_a fused into stage0; + prop_xr aux
    run_cell(4, nullptr, 0, 2, false);   // + sgc2 aux
    run_cell(8, nullptr, 0, 3, false);   // + short head aux
    run_cell(12, nullptr, 0, 0, false);
    run_cell(16, nullptr, 0, 0, false);

    run_cell(-1, xshort, 1, 0, false);
}

// Round 5
// 589.552 us; speedup vs baseline: 9.4668x; 1.0288x over previous
//
#include <hip/hip_runtime.h>

// PSGIN forward on MI355X. fp32 I/O. Multi-kernel pipeline.
// R11 (630us): stage0 merge. R13 (628us): poly tanh. R14 (630us): P^2 algebra + aux absorption.
// Fit: T = 9us/link * links + work. R15/R16 FAILED: persistent kernel 5581us — grid-barrier
// fences flush per-XCD L2 (250MB refetch); structurally dead on 8-XCD gfx950.
// R17 (606us): cell0 cell_a fused into stage0 (-1 link); cell_bP 8-row tiles.
// R18: pg = P@g0 materialized (520-block link, 1 round) -> z/r gate single-prop
// (g2 = a*g0 + a*pg + P@pg, inner loop halves); P^2 tiles ride the z/r launch (only the
// c-gate consumes P^2). Gate smem 50.8->30KB (sX/sW union) -> 5 blocks/CU.

constexpr int B = 8, T = 24, N = 207, F = 16, H = 64, DH = 16;
constexpr int PS = 208; // padded stride for N x N matrices
constexpr float ALPHA = 0.05f, BETA = 0.95f, GAMMA = 0.95f, TA = 2.0f;
constexpr int NF = N * F;      // 3312
constexpr int BNF = B * N * F; // 26496

__device__ __forceinline__ float tanh_fast(float x) { float e = __expf(2.f * x); return 1.f - 2.f / (e + 1.f); }
__device__ __forceinline__ float sigm(float x) { return 1.f / (1.f + __expf(-x)); }
// cubic/quintic series tanh: x*(1 + x2*(-1/3 + (2/15)x2)); |err|<1e-3 for |x|<0.6.
__device__ __forceinline__ float tanh_poly(float x) {
    float x2 = x * x;
    float c = __builtin_fmaf(x2, 0.13333333f, -0.33333333f);
    return x * __builtin_fmaf(x2, c, 1.f);
}

// =============== stage 0: Ts transpose + A2 = (adj@adj)^T + attention scores + cell0 s,t ===============
// grid x: [0,49) A2; [49,217) Ts; [217,1785) attn 32x32 tiles; [1785,1889) cell0 cell_a (h=0)
__global__ __launch_bounds__(256) void k_stage0(
    const float* __restrict__ adj, const float* __restrict__ inp,
    const float* __restrict__ Wq, const float* __restrict__ Wk,
    const float* __restrict__ kb, const float* __restrict__ sw_,
    const float* __restrict__ Wes, const float* __restrict__ bes,
    const float* __restrict__ Wet, const float* __restrict__ bet,
    const float* __restrict__ bsrc, const float* __restrict__ btgt,
    float* __restrict__ Ts, float* __restrict__ A2,
    float* __restrict__ attnT, float* __restrict__ rsum,
    float* __restrict__ s_out, float* __restrict__ t_out, float* __restrict__ catg)
{
    __shared__ __align__(16) float smem[7424];
    int bid = blockIdx.x, tid = threadIdx.x;
    if (bid < 49) {
        int vb = (bid % 7) * 32, wb = (bid / 7) * 32;
        float* sA = smem;          // [32][33]
        float* sB = smem + 1056;   // [32][33]
        float acc[4] = {0, 0, 0, 0};
        int i0 = tid >> 5, j = tid & 31;
        for (int u0 = 0; u0 < N; u0 += 32) {
            __syncthreads();
            for (int l = tid; l < 1024; l += 256) {
                int i = l >> 5, jj = l & 31;
                int v = vb + i, u = u0 + jj;
                sA[i * 33 + jj] = (v < N && u < N) ? adj[v * N + u] : 0.f;
                int uu = u0 + i, w = wb + jj;
                sB[i * 33 + jj] = (uu < N && w < N) ? adj[uu * N + w] : 0.f;
            }
            __syncthreads();
#pragma unroll 8
            for (int u = 0; u < 32; u++) {
                float bv = sB[u * 33 + j];
#pragma unroll
                for (int k = 0; k < 4; k++) acc[k] += sA[(i0 + k * 8) * 33 + u] * bv;
            }
        }
#pragma unroll
        for (int k = 0; k < 4; k++) {
            int v = vb + i0 + k * 8, w = wb + j;
            if (v < N && w < N) A2[(size_t)w * PS + v] = acc[k];
        }
    } else if (bid < 217) {
        int i = (bid - 49) * 256 + tid;
        if (i < N * N) {
            int w = i / N, v = i % N;
            Ts[(size_t)w * PS + v] = adj[v * N + w];
        }
    } else if (bid < 1785) {
        int idx = bid - 217;
        int bt = idx / 49, rem = idx % 49;
        int n0 = (rem % 7) * 32, m0 = (rem / 7) * 32;
        int b = bt >> 2, tau = bt & 3;
        int ti = tid >> 4, tj = tid & 15;
        float* sQ = smem;            // 32*65
        float* sK = smem + 2080;     // 32*65
        float* sWq = smem + 4160;    // 16*64
        float* sWk = smem + 5184;    // 16*64
        float* sXq = smem + 6208;    // 32*17
        float* sXk = smem + 6752;    // 32*17
        float* ssw = smem + 7296;    // 64
        float* skb = smem + 7360;    // 64
        const float* xq = inp + ((size_t)(b * T + (T - 1))) * NF;
        const float* xk = inp + ((size_t)(b * T + 20 + tau)) * NF;
        {
            float4 wq4 = *(const float4*)&Wq[tid * 4];
            float4 wk4 = *(const float4*)&Wk[tid * 4];
            *(float4*)&sWq[(tid >> 4) * 64 + (tid & 15) * 4] = wq4;
            *(float4*)&sWk[(tid >> 4) * 64 + (tid & 15) * 4] = wk4;
            if (tid < 64) { ssw[tid] = sw_[tid]; skb[tid] = kb[tid]; }
            int i2 = tid & 127;
            int r = i2 >> 2, c4 = (i2 & 3) * 4;
            if (tid < 128) {
                float4 aq = make_float4(0, 0, 0, 0);
                int n = n0 + r;
                if (n < N) aq = *(const float4*)&xq[(size_t)n * F + c4];
                sXq[r * 17 + c4] = aq.x; sXq[r * 17 + c4 + 1] = aq.y; sXq[r * 17 + c4 + 2] = aq.z; sXq[r * 17 + c4 + 3] = aq.w;
            } else {
                float4 ck = make_float4(0, 0, 0, 0);
                int m = m0 + r;
                if (m < N) ck = *(const float4*)&xk[(size_t)m * F + c4];
                sXk[r * 17 + c4] = ck.x; sXk[r * 17 + c4 + 1] = ck.y; sXk[r * 17 + c4 + 2] = ck.z; sXk[r * 17 + c4 + 3] = ck.w;
            }
        }
        __syncthreads();
        {
            int r = tid >> 3, o0 = (tid & 7) * 8;
            float xr[16], xkr[16];
#pragma unroll
            for (int f = 0; f < 16; f++) { xr[f] = sXq[r * 17 + f]; xkr[f] = sXk[r * 17 + f]; }
#pragma unroll
            for (int j = 0; j < 8; j++) {
                int o = o0 + j;
                float aq = 0.f, ak = skb[o];
#pragma unroll
                for (int f = 0; f < 16; f++) { aq += xr[f] * sWq[f * 64 + o]; ak += xkr[f] * sWk[f * 64 + o]; }
                sQ[r * 65 + o] = aq; sK[r * 65 + o] = ak;
            }
        }
        __syncthreads();
        float s00 = 0.f, s01 = 0.f, s10 = 0.f, s11 = 0.f;
#pragma unroll 2
        for (int d = 0; d < 64; d++) {
            float w = ssw[d];
            float q1 = sQ[ti * 65 + d], q2 = sQ[(ti + 16) * 65 + d];
            float k1 = sK[tj * 65 + d], k2 = sK[(tj + 16) * 65 + d];
            s00 += tanh_poly(q1 + k1) * w;
            s01 += tanh_poly(q1 + k2) * w;
            s10 += tanh_poly(q2 + k1) * w;
            s11 += tanh_poly(q2 + k2) * w;
        }
        int n1 = n0 + ti, n2 = n0 + ti + 16, m1 = m0 + tj, m2 = m0 + tj + 16;
        bool vn1 = n1 < N, vn2 = n2 < N, vm1 = m1 < N, vm2 = m2 < N;
        float e00 = (vn1 && vm1) ? __expf(s00) : 0.f;
        float e01 = (vn1 && vm2) ? __expf(s01) : 0.f;
        float e10 = (vn2 && vm1) ? __expf(s10) : 0.f;
        float e11 = (vn2 && vm2) ? __expf(s11) : 0.f;
        float part1 = e00 + e01, part2 = e10 + e11;
        for (int d = 8; d > 0; d >>= 1) {
            part1 += __shfl_down(part1, d, 16);
            part2 += __shfl_down(part2, d, 16);
        }
        if (tj == 0) {
            if (vn1) atomicAdd(&rsum[bt * N + n1], part1);
            if (vn2) atomicAdd(&rsum[bt * N + n2], part2);
        }
        __syncthreads();
        float* tile = sQ;  // 32x33
        tile[tj * 33 + ti] = e00;
        tile[(tj + 16) * 33 + ti] = e01;
        tile[tj * 33 + ti + 16] = e10;
        tile[(tj + 16) * 33 + ti + 16] = e11;
        __syncthreads();
        {
            int row = tid >> 3, c4 = (tid & 7) * 4;
            int m = m0 + row;
            if (m < N) {
                float4 v = make_float4(tile[row * 33 + c4], tile[row * 33 + c4 + 1],
                                       tile[row * 33 + c4 + 2], tile[row * 33 + c4 + 3]);
                *(float4*)&attnT[(size_t)bt * PS * PS + (size_t)m * PS + n0 + c4] = v;
            }
        }
    } else {
        // cell0 cell_a, h = 0: ctx = bias; s = tanh(TA*(x@Wes+bes)*bsrc), t likewise.
        int idx = bid - 1785;
        int x13 = idx % 13, b = idx / 13;
        int w0 = x13 * 16;
        int ty = tid >> 4, tx = tid & 15;
        float* sX  = smem;        // [16][17]
        float* sWs = smem + 272;  // [16][16]
        float* sWt = smem + 528;  // [16][16]
        const float* xp = inp + ((size_t)(b * T + 0)) * NF;
        {
            int w = w0 + ty;
            sX[ty * 17 + tx] = (w < N) ? xp[(size_t)w * F + tx] : 0.f;
            sWs[ty * 16 + tx] = Wes[ty * 16 + tx];
            sWt[ty * 16 + tx] = Wet[ty * 16 + tx];
        }
        __syncthreads();
        float xs = bes[tx], xt = bet[tx];
#pragma unroll
        for (int f = 0; f < 16; f++) {
            float xv = sX[ty * 17 + f];
            xs += xv * sWs[f * 16 + tx];
            xt += xv * sWt[f * 16 + tx];
        }
        int w = w0 + ty;
        if (w < N) {
            s_out[((size_t)(b * N + w)) * DH + tx] = tanh_fast(TA * xs * bsrc[tx]);
            t_out[((size_t)(b * N + w)) * DH + tx] = tanh_fast(TA * xt * btgt[tx]);
            // catg for cell0: [x | h=0]
            catg[((size_t)(b * N + w)) * 80 + tx] = sX[ty * 17 + tx];
#pragma unroll
            for (int j = 0; j < 4; j++) catg[((size_t)(b * N + w)) * 80 + 16 + tx * 4 + j] = 0.f;
        }
    }
}

// ---------------- cell stage A (lane-split): hyper chain + one projection per lane ----------------
__global__ __launch_bounds__(256) void k_cell_a(
    const float* __restrict__ h, const float* __restrict__ Ts, const float* __restrict__ A2,
    const float* __restrict__ xseq, int tsel, const float* __restrict__ xbuf,
    const float* __restrict__ Wsrc, const float* __restrict__ bsrc,
    const float* __restrict__ Wtgt, const float* __restrict__ btgt,
    const float* __restrict__ Wes, const float* __restrict__ bes,
    const float* __restrict__ Wet, const float* __restrict__ bet,
    float* __restrict__ s_out, float* __restrict__ t_out, float* __restrict__ catg) {
    int b = blockIdx.y, w0 = blockIdx.x * 16, lane = blockIdx.z;
    int tid = threadIdx.x, ty = tid >> 4, tx = tid & 15;
    __shared__ float sTs[2][16][33], sA2[2][16][33];
    __shared__ float sH[2][32][64];
    __shared__ float cat[16][193];
    __shared__ float sW[192][16];
    __shared__ float sX[16][16], sWe[16][16];
    float au[4] = {0, 0, 0, 0}, aw[4] = {0, 0, 0, 0};
    const float* hb = h + b * N * H;
    const float* xp = (tsel >= 0) ? (xseq + ((size_t)(b * T + tsel)) * NF) : (xbuf + (size_t)b * NF);
    int pidx = tid & 127;
    int pr = pidx >> 3, pc4 = (pidx & 7) * 4;
    float4 t4;
    float4 h4[2];
    int hr[2], hc[2];
#pragma unroll
    for (int k = 0; k < 2; k++) { int l4 = tid + k * 256; hr[k] = l4 >> 4; hc[k] = (l4 & 15) * 4; }
    auto loadT = [&](int v0) {
        t4 = make_float4(0, 0, 0, 0);
        const float* src = (tid < 128) ? Ts : A2;
        int w = w0 + pr;
        if (w < N) t4 = *(const float4*)&src[(size_t)w * PS + v0 + pc4];
#pragma unroll
        for (int k = 0; k < 2; k++) {
            float4 hv = make_float4(0, 0, 0, 0);
            int v = v0 + hr[k];
            if (v < N) hv = *(const float4*)&hb[(size_t)v * H + hc[k]];
            h4[k] = hv;
        }
    };
    loadT(0);
    int cur = 0;
    for (int t = 0; t < 7; t++) {
        __syncthreads();
        {
            float (*dst)[33] = (tid < 128) ? sTs[cur] : sA2[cur];
            dst[pr][pc4] = t4.x; dst[pr][pc4 + 1] = t4.y; dst[pr][pc4 + 2] = t4.z; dst[pr][pc4 + 3] = t4.w;
        }
#pragma unroll
        for (int k = 0; k < 2; k++) *(float4*)&sH[cur][hr[k]][hc[k]] = h4[k];
        if (t < 6) loadT((t + 1) * 32);
        __syncthreads();
#pragma unroll 8
        for (int v = 0; v < 32; v++) {
            float pu = sTs[cur][ty][v], pw = sA2[cur][ty][v];
#pragma unroll
            for (int j = 0; j < 4; j++) {
                float x = sH[cur][v][tx * 4 + j];
                au[j] += pu * x; aw[j] += pw * x;
            }
        }
        cur ^= 1;
    }
    int w = w0 + ty;
    bool valid = w < N;
    __syncthreads();
    if (valid) {
#pragma unroll
        for (int j = 0; j < 4; j++) {
            int c = tx * 4 + j;
            float hv = hb[(size_t)w * H + c];
            float u = au[j], w2 = aw[j];
            cat[ty][c] = hv;
            cat[ty][64 + c] = ALPHA * hv + GAMMA * u;
            cat[ty][128 + c] = ALPHA * hv + ALPHA * GAMMA * u + GAMMA * GAMMA * w2;
        }
    } else {
#pragma unroll
        for (int j = 0; j < 4; j++) {
            int c = tx * 4 + j;
            cat[ty][c] = 0; cat[ty][64 + c] = 0; cat[ty][128 + c] = 0;
        }
    }
    const float* Wg = lane ? Wtgt : Wsrc;
    const float* bg = lane ? btgt : bsrc;
    const float* We = lane ? Wet : Wes;
    const float* be = lane ? bet : bes;
    {
        float4 wv[3];
#pragma unroll
        for (int k = 0; k < 3; k++) wv[k] = *(const float4*)&Wg[(tid + k * 256) * 4];
        float4 xv = make_float4(0, 0, 0, 0), ev = make_float4(0, 0, 0, 0);
        int sr = 0, sc = 0;
        if (tid < 64) {
            sr = tid >> 2; sc = (tid & 3) * 4;
            int n = w0 + sr;
            if (n < N) xv = *(const float4*)&xp[(size_t)n * F + sc];
            ev = *(const float4*)&We[tid * 4];
        }
#pragma unroll
        for (int k = 0; k < 3; k++) {
            int l4 = tid + k * 256;
            int r = l4 >> 2, c4 = (l4 & 3) * 4;
            *(float4*)&sW[r][c4] = wv[k];
        }
        if (tid < 64) {
            *(float4*)&sX[sr][sc] = xv;
            *(float4*)&sWe[sr][sc] = ev;
        }
    }
    __syncthreads();
    if (lane == 0 && valid) {
#pragma unroll
        for (int j = 0; j < 5; j++) {
            int c = tx * 5 + j;
            float v = (c < 16) ? sX[ty][c] : hb[(size_t)w * H + (c - 16)];
            catg[((size_t)(b * N + w)) * 80 + c] = v;
        }
    }
    {
        float ctx = bg[tx];
#pragma unroll 8
        for (int c = 0; c < 192; c++) ctx += cat[ty][c] * sW[c][tx];
        float xe = be[tx];
#pragma unroll
        for (int f = 0; f < 16; f++) xe += sX[ty][f] * sWe[f][tx];
        if (valid) {
            float val = tanh_fast(TA * xe * ctx);
            if (lane == 0) s_out[(size_t)(b * N + w) * DH + tx] = val;
            else           t_out[(size_t)(b * N + w) * DH + tx] = val;
        }
    }
}

// ---------------- cell stage B: 8-row v-tiles, grid (26, B) ----------------
__global__ __launch_bounds__(256) void k_cell_bP(const float* __restrict__ s_in, const float* __restrict__ t_in,
                                                 const float* __restrict__ adj, float* __restrict__ P) {
    int b = blockIdx.y, v0 = blockIdx.x * 8;
    int tid = threadIdx.x, ty = tid >> 5, tx = tid & 31;
    __shared__ float sS[N][17], sT[N][17];
    for (int l4 = tid; l4 < 828; l4 += 256) {
        float4 sv = *(const float4*)&s_in[(size_t)b * N * 16 + l4 * 4];
        float4 tv = *(const float4*)&t_in[(size_t)b * N * 16 + l4 * 4];
        int r = l4 >> 2, c = (l4 & 3) * 4;
        sS[r][c] = sv.x; sS[r][c + 1] = sv.y; sS[r][c + 2] = sv.z; sS[r][c + 3] = sv.w;
        sT[r][c] = tv.x; sT[r][c + 1] = tv.y; sT[r][c + 2] = tv.z; sT[r][c + 3] = tv.w;
    }
    __syncthreads();
    int v = v0 + ty;
    bool valid = v < N;
    int vc = valid ? v : (N - 1);
    float sv[16], tv[16];
#pragma unroll
    for (int k = 0; k < 16; k++) { sv[k] = sS[vc][k]; tv[k] = sT[vc][k]; }
    float val[7];
    float rsum = 0.f;
#pragma unroll
    for (int idx = 0; idx < 7; idx++) {
        int w = tx + 32 * idx;
        float r = 0.f;
        if (w < N) {
            float a = 0.f;
#pragma unroll
            for (int k = 0; k < 16; k++) a += sv[k] * sT[w][k] - tv[k] * sS[w][k];
            r = tanh_fast(TA * a);
            r = r > 0.f ? r : 0.f;
            if (w == v) r += 1.f;
        }
        val[idx] = r;
        rsum += r;
    }
    float tot = rsum;
    for (int d = 16; d > 0; d >>= 1) tot += __shfl_down(tot, d, 32);
    tot = __shfl(tot, 0, 32);
    float rinv = BETA / (tot + 1e-8f);
    if (valid) {
        float* Pb = P + (size_t)b * PS * PS;
#pragma unroll
        for (int idx = 0; idx < 7; idx++) {
            int w = tx + 32 * idx;
            if (w < N) Pb[(size_t)w * PS + v] = val[idx] * rinv + GAMMA * adj[v * N + w];
        }
    }
}

// ---------------- aux bodies (fused into k_pg launches; carved smem union) ----------------
__device__ __forceinline__ void body_prop_xr(float* smem, int w0, int bt,
    const float* __restrict__ attnT, const float* __restrict__ rsum,
    const float* __restrict__ Ts, const float* __restrict__ inp, float* __restrict__ x1)
{
    int b = bt >> 2, tau = bt & 3;
    const float* xb = inp + ((size_t)(b * T + 20 + tau)) * NF;
    const float* PA = attnT + (size_t)bt * PS * PS;
    int tid = threadIdx.x, ty = tid >> 4, tx = tid & 15;
    float (*sPA)[16][33] = (float(*)[16][33])(smem);
    float (*sPT)[16][33] = (float(*)[16][33])(smem + 1056);
    float (*sX)[32][17]  = (float(*)[32][17])(smem + 2112);
    float (*sXs)[32][17] = (float(*)[32][17])(smem + 3200);
    float accA = 0.f, accT = 0.f;
    int prr = tid >> 3, pcc = (tid & 7) * 4;
    int xrr = (tid - 128) >> 2, xcc = ((tid - 128) & 3) * 4;
    float4 pa, pt, xv;
    float rinv_;
    auto loadT = [&](int v0) {
        pa = make_float4(0, 0, 0, 0); pt = make_float4(0, 0, 0, 0); xv = make_float4(0, 0, 0, 0); rinv_ = 0.f;
        if (tid < 128) {
            int w = w0 + prr;
            if (w < N) {
                pa = *(const float4*)&PA[(size_t)w * PS + v0 + pcc];
                pt = *(const float4*)&Ts[(size_t)w * PS + v0 + pcc];
            }
        } else {
            int v = v0 + xrr;
            if (v < N) {
                xv = *(const float4*)&xb[(size_t)v * F + xcc];
                rinv_ = __builtin_amdgcn_rcpf(rsum[bt * N + v]);
            }
        }
    };
    loadT(0);
    int cur = 0;
    for (int t = 0; t < 7; t++) {
        __syncthreads();
        if (tid < 128) {
            sPA[cur][prr][pcc] = pa.x; sPA[cur][prr][pcc + 1] = pa.y; sPA[cur][prr][pcc + 2] = pa.z; sPA[cur][prr][pcc + 3] = pa.w;
            sPT[cur][prr][pcc] = pt.x; sPT[cur][prr][pcc + 1] = pt.y; sPT[cur][prr][pcc + 2] = pt.z; sPT[cur][prr][pcc + 3] = pt.w;
        } else {
            sX[cur][xrr][xcc] = xv.x; sX[cur][xrr][xcc + 1] = xv.y; sX[cur][xrr][xcc + 2] = xv.z; sX[cur][xrr][xcc + 3] = xv.w;
            sXs[cur][xrr][xcc] = xv.x * rinv_; sXs[cur][xrr][xcc + 1] = xv.y * rinv_;
            sXs[cur][xrr][xcc + 2] = xv.z * rinv_; sXs[cur][xrr][xcc + 3] = xv.w * rinv_;
        }
        if (t < 6) loadT((t + 1) * 32);
        __syncthreads();
#pragma unroll 8
        for (int v = 0; v < 32; v++) {
            accA += sPA[cur][ty][v] * sXs[cur][v][tx];
            accT += sPT[cur][ty][v] * sX[cur][v][tx];
        }
        cur ^= 1;
    }
    int w = w0 + ty;
    if (w < N) x1[((size_t)(bt * N + w)) * 16 + tx] = ALPHA * xb[w * F + tx] + GAMMA * (accA + accT);
}

__device__ __forceinline__ void body_sgc2(float* smem, int w0, int bt,
    const float* __restrict__ attnT, const float* __restrict__ rsum,
    const float* __restrict__ Ts, const float* __restrict__ x1, const float* __restrict__ inp,
    const float* __restrict__ Ws, const float* __restrict__ bs, float* __restrict__ target)
{
    int b = bt >> 2, tau = bt & 3;
    const float* xb = inp + ((size_t)(b * T + 20 + tau)) * NF;
    const float* PA = attnT + (size_t)bt * PS * PS;
    int tid = threadIdx.x, ty = tid >> 4, tx = tid & 15;
    float (*sPA)[16][33] = (float(*)[16][33])(smem);
    float (*sPT)[16][33] = (float(*)[16][33])(smem + 1056);
    float (*sX)[32][17]  = (float(*)[32][17])(smem + 2112);
    float (*sXs)[32][17] = (float(*)[32][17])(smem + 3200);
    float (*scat)[48]    = (float(*)[48])(smem + 4288);
    float (*sWs)[64]     = (float(*)[64])(smem + 5056);
    float accA = 0.f, accT = 0.f;
    int prr = tid >> 3, pcc = (tid & 7) * 4;
    int xrr = (tid - 128) >> 2, xcc = ((tid - 128) & 3) * 4;
    float4 pa, pt, xv;
    float rinv_;
    auto loadT = [&](int v0) {
        pa = make_float4(0, 0, 0, 0); pt = make_float4(0, 0, 0, 0); xv = make_float4(0, 0, 0, 0); rinv_ = 0.f;
        if (tid < 128) {
            int w = w0 + prr;
            if (w < N) {
                pa = *(const float4*)&PA[(size_t)w * PS + v0 + pcc];
                pt = *(const float4*)&Ts[(size_t)w * PS + v0 + pcc];
            }
        } else {
            int v = v0 + xrr;
            if (v < N) {
                xv = *(const float4*)&x1[((size_t)(bt * N + v)) * 16 + xcc];
                rinv_ = __builtin_amdgcn_rcpf(rsum[bt * N + v]);
            }
        }
    };
    loadT(0);
    int cur = 0;
    for (int t = 0; t < 7; t++) {
        __syncthreads();
        if (tid < 128) {
            sPA[cur][prr][pcc] = pa.x; sPA[cur][prr][pcc + 1] = pa.y; sPA[cur][prr][pcc + 2] = pa.z; sPA[cur][prr][pcc + 3] = pa.w;
            sPT[cur][prr][pcc] = pt.x; sPT[cur][prr][pcc + 1] = pt.y; sPT[cur][prr][pcc + 2] = pt.z; sPT[cur][prr][pcc + 3] = pt.w;
        } else {
            sX[cur][xrr][xcc] = xv.x; sX[cur][xrr][xcc + 1] = xv.y; sX[cur][xrr][xcc + 2] = xv.z; sX[cur][xrr][xcc + 3] = xv.w;
            sXs[cur][xrr][xcc] = xv.x * rinv_; sXs[cur][xrr][xcc + 1] = xv.y * rinv_;
            sXs[cur][xrr][xcc + 2] = xv.z * rinv_; sXs[cur][xrr][xcc + 3] = xv.w * rinv_;
        }
        if (t < 6) loadT((t + 1) * 32);
        __syncthreads();
#pragma unroll 8
        for (int v = 0; v < 32; v++) {
            accA += sPA[cur][ty][v] * sXs[cur][v][tx];
            accT += sPT[cur][ty][v] * sX[cur][v][tx];
        }
        cur ^= 1;
    }
    int w = w0 + ty;
    bool valid = w < N;
    __syncthreads();
    for (int l = tid; l < 512; l += 256) {
        int i = l >> 5, c = l & 31;
        int ww = w0 + i;
        float vv = 0;
        if (ww < N) {
            if (c < 16) vv = xb[ww * F + c];
            else vv = x1[((size_t)bt * N + ww) * 16 + (c - 16)];
        }
        scat[i][c] = vv;
    }
    {
        float x0 = valid ? xb[w * F + tx] : 0.f;
        scat[ty][32 + tx] = ALPHA * x0 + GAMMA * (accA + accT);
    }
    {
        float4 wv[3];
#pragma unroll
        for (int k = 0; k < 3; k++) wv[k] = *(const float4*)&Ws[(tid + k * 256) * 4];
#pragma unroll
        for (int k = 0; k < 3; k++) {
            int l4 = tid + k * 256;
            *(float4*)&sWs[l4 >> 4][(l4 & 15) * 4] = wv[k];
        }
    }
    __syncthreads();
    float acc[4];
#pragma unroll
    for (int j = 0; j < 4; j++) acc[j] = bs[tx * 4 + j];
#pragma unroll 8
    for (int cc = 0; cc < 48; cc++) {
        float cv = scat[ty][cc];
        float4 w4 = *(const float4*)&sWs[cc][tx * 4];
        acc[0] += cv * w4.x; acc[1] += cv * w4.y; acc[2] += cv * w4.z; acc[3] += cv * w4.w;
    }
    if (valid) {
#pragma unroll
        for (int j = 0; j < 4; j++) {
            float r = acc[j] > 0.f ? acc[j] : 0.f;
            atomicAdd(&target[(b * N + w) * 64 + tx * 4 + j], r);
        }
    }
}

__device__ __forceinline__ void body_short(float* smem, int n0, int b,
    const float* __restrict__ target, const float* __restrict__ Wsh, const float* __restrict__ bsh,
    float* __restrict__ out, float* __restrict__ xshort)
{
    int tid = threadIdx.x, ty = tid >> 4, tx = tid & 15;
    float (*trow)[65] = (float(*)[65])(smem);
    float (*sW)[16]   = (float(*)[16])(smem + 1040);
    {
        int r = tid >> 4, c4 = (tid & 15) * 4;
        int n = n0 + r;
        float4 tv = make_float4(0, 0, 0, 0);
        if (n < N) tv = *(const float4*)&target[((size_t)(b * N + n)) * 64 + c4];
        trow[r][c4] = tv.x; trow[r][c4 + 1] = tv.y; trow[r][c4 + 2] = tv.z; trow[r][c4 + 3] = tv.w;
        float4 wv = *(const float4*)&Wsh[tid * 4];
        *(float4*)&sW[tid >> 2][(tid & 3) * 4] = wv;
    }
    __syncthreads();
    float acc = bsh[tx];
#pragma unroll 8
    for (int o = 0; o < 64; o++) acc += trow[ty][o] * sW[o][tx];
    int n = n0 + ty;
    if (n < N) {
        out[((size_t)0 * B * N + b * N + n) * 16 + tx] = acc;
        xshort[(b * N + n) * 16 + tx] = acc;
    }
}

// ---------------- pg = P @ g0 (520 blocks, 1 round) + aux tail ----------------
// grid x: [0,520) pg 16x16 tiles (13*B*5); [520,...) aux (prop_xr / sgc2 / short)
__global__ __launch_bounds__(256) void k_pg(
    const float* __restrict__ P, const float* __restrict__ cat, float* __restrict__ pg, int aux,
    const float* __restrict__ attnT, const float* __restrict__ rsum,
    const float* __restrict__ Ts, const float* __restrict__ inp, float* __restrict__ x1,
    const float* __restrict__ Ws, const float* __restrict__ bs, float* __restrict__ target,
    const float* __restrict__ Wsh, const float* __restrict__ bsh,
    float* __restrict__ out, float* __restrict__ xshort)
{
    __shared__ __align__(16) float smem[8128];
    int bid = blockIdx.x, tid = threadIdx.x;
    if (bid < 520) {
        int x13 = bid % 13, b = (bid / 13) & 7, z = bid / 104;
        int w0 = x13 * 16, c0 = z * 16;
        int ty = tid >> 4, tx = tid & 15;
        const float* Pb = P + (size_t)b * PS * PS;
        float (*sP)[16][33] = (float(*)[16][33])(smem);
        float (*sX)[32][17] = (float(*)[32][17])(smem + 1056);
        float a1 = 0.f;
        int pr = tid >> 4, pc = (tid & 15) * 2;
        int xr = tid >> 3, xc = (tid & 7) * 2;
        float2 pv, xv;
        auto loadT = [&](int v0) {
            pv = make_float2(0, 0); xv = make_float2(0, 0);
            int w = w0 + pr;
            if (w < N) pv = *(const float2*)&Pb[(size_t)w * PS + v0 + pc];
            int vv = v0 + xr;
            if (vv < N) xv = *(const float2*)&cat[((size_t)(b * N + vv)) * 80 + c0 + xc];
        };
        loadT(0);
        int cur = 0;
        for (int t = 0; t < 7; t++) {
            __syncthreads();
            sP[cur][pr][pc] = pv.x; sP[cur][pr][pc + 1] = pv.y;
            sX[cur][xr][xc] = xv.x; sX[cur][xr][xc + 1] = xv.y;
            if (t < 6) loadT((t + 1) * 32);
            __syncthreads();
#pragma unroll 8
            for (int v_ = 0; v_ < 32; v_++) a1 += sP[cur][ty][v_] * sX[cur][v_][tx];
            cur ^= 1;
        }
        int w = w0 + ty;
        if (w < N) pg[((size_t)(b * N + w)) * 80 + c0 + tx] = a1;
    } else {
        int idx = bid - 520;
        if (aux == 1)      body_prop_xr(smem, (idx % 13) * 16, idx / 13, attnT, rsum, Ts, inp, x1);
        else if (aux == 2) body_sgc2(smem, (idx % 13) * 16, idx / 13, attnT, rsum, Ts, x1, inp, Ws, bs, target);
        else               body_short(smem, (idx % 13) * 16, idx / 13, target, Wsh, bsh, out, xshort);
    }
}

// ---------------- z/r gates (single-prop over pg) + P^2 tiles riding ----------------
// grid x: [0,208) z/r gate tiles (mode = bid/104); [208, 1560) P^2 16x16 tiles.
// g1 = a*g0 + pg ; g2 = a*g0 + a*pg + P@pg. P^2 consumed only by the c-gate (next launch).
__global__ __launch_bounds__(256) void k_gatezr(
    const float* __restrict__ catg, const float* __restrict__ pg,
    const float* __restrict__ P, float* __restrict__ P2,
    const float* __restrict__ Wz, const float* __restrict__ bz,
    const float* __restrict__ Wr, const float* __restrict__ br,
    const float* __restrict__ xseq, int tsel, const float* __restrict__ xbuf,
    float* __restrict__ zbuf, float* __restrict__ catc,
    const float* __restrict__ h)
{
    __shared__ __align__(16) float smem[7504];
    int bid = blockIdx.x, tid = threadIdx.x;
    if (bid < 208) {
        int mode = bid / 104, rem = bid % 104;
        int x13 = rem % 13, b = rem / 13;
        int w0 = x13 * 16;
        int ty = tid >> 4, tx = tid & 15;
        const float* W = mode ? Wr : Wz;
        const float* bias = mode ? br : bz;
        const float* Pb = P + (size_t)b * PS * PS;
        float (*sC)[241] = (float(*)[241])(smem);          // 3856
        float (*sP)[33]  = (float(*)[33])(smem + 3856);    // 528
        float (*sX)[81]  = (float(*)[81])(smem + 4384);    // 2592 (phase A)
        float (*sW)[65]  = (float(*)[65])(smem + 4384);    // 3120 (phase B, union w/ sX)
        // load g0 (80 cols)
        for (int l4 = tid; l4 < 320; l4 += 256) {
            int r = l4 / 20, c4 = (l4 % 20) * 4;
            int w = w0 + r;
            float4 v4 = make_float4(0, 0, 0, 0);
            if (w < N) v4 = *(const float4*)&catg[((size_t)(b * N + w)) * 80 + c4];
            sC[r][c4] = v4.x; sC[r][c4 + 1] = v4.y; sC[r][c4 + 2] = v4.z; sC[r][c4 + 3] = v4.w;
        }
        // phase A: accP = P @ pg (single prop)
        float accP[5] = {0, 0, 0, 0, 0};
        int prr = tid >> 4, prc = (tid & 15) * 2;
        int xrow = tid & 31, xc0 = (tid >> 5) * 10;
        float2 pv;
        float2 xv[5];
        auto loadT = [&](int v0) {
            pv = make_float2(0, 0);
            int w = w0 + prr;
            if (w < N) pv = *(const float2*)&Pb[(size_t)w * PS + v0 + prc];
            int v = v0 + xrow;
#pragma unroll
            for (int k = 0; k < 5; k++) xv[k] = make_float2(0, 0);
            if (v < N) {
                const float* src = &pg[((size_t)(b * N + v)) * 80 + xc0];
#pragma unroll
                for (int k = 0; k < 5; k++) xv[k] = *(const float2*)&src[k * 2];
            }
        };
        loadT(0);
        for (int t = 0; t < 7; t++) {
            __syncthreads();
            sP[prr][prc] = pv.x; sP[prr][prc + 1] = pv.y;
#pragma unroll
            for (int k = 0; k < 5; k++) { sX[xrow][xc0 + 2 * k] = xv[k].x; sX[xrow][xc0 + 2 * k + 1] = xv[k].y; }
            if (t < 6) loadT((t + 1) * 32);
            __syncthreads();
#pragma unroll 8
            for (int v = 0; v < 32; v++) {
                float p = sP[ty][v];
#pragma unroll
                for (int j = 0; j < 5; j++) accP[j] += p * sX[v][tx * 5 + j];
            }
        }
        int w = w0 + ty;
        bool valid = w < N;
        // own-row pg + fill g1/g2 cols
#pragma unroll
        for (int j = 0; j < 5; j++) {
            int c = tx * 5 + j;
            float pgo = valid ? pg[((size_t)(b * N + w)) * 80 + c] : 0.f;
            float g0 = sC[ty][c];
            sC[ty][80 + c]  = ALPHA * g0 + pgo;
            sC[ty][160 + c] = ALPHA * g0 + ALPHA * pgo + accP[j];
        }
        // phase B: GEMM over 240 cols with register prefetch (sW overwrites sX after sync)
        float4 wv[3];
#pragma unroll
        for (int k = 0; k < 3; k++) wv[k] = *(const float4*)&W[(tid + k * 256) * 4];
        float ga[4];
#pragma unroll
        for (int j = 0; j < 4; j++) ga[j] = bias[tx * 4 + j];
        for (int ch = 0; ch < 5; ch++) {
            __syncthreads();
#pragma unroll
            for (int k = 0; k < 3; k++) {
                int l4 = tid + k * 256;
                int r = l4 >> 4, cc = (l4 & 15) * 4;
                sW[r][cc] = wv[k].x; sW[r][cc + 1] = wv[k].y; sW[r][cc + 2] = wv[k].z; sW[r][cc + 3] = wv[k].w;
            }
            if (ch < 4) {
#pragma unroll
                for (int k = 0; k < 3; k++) wv[k] = *(const float4*)&W[(size_t)(ch + 1) * 3072 + (tid + k * 256) * 4];
            }
            __syncthreads();
            int c0 = ch * 48;
#pragma unroll 8
            for (int cc = 0; cc < 48; cc++) {
                float cv = sC[ty][c0 + cc];
#pragma unroll
                for (int j = 0; j < 4; j++) ga[j] += cv * sW[cc][tx * 4 + j];
            }
        }
        if (mode == 0) {
            if (valid) {
#pragma unroll
                for (int j = 0; j < 4; j++) zbuf[((size_t)(b * N + w)) * 64 + tx * 4 + j] = sigm(ga[j]);
            }
        } else {
            if (valid) {
#pragma unroll
                for (int j = 0; j < 4; j++) {
                    int o = tx * 4 + j;
                    catc[((size_t)(b * N + w)) * 80 + 16 + o] = sigm(ga[j]) * h[((size_t)(b * N + w)) * 64 + o];
                }
                if (tx < 4) {
                    const float* xp = (tsel >= 0) ? (xseq + ((size_t)(b * T + tsel)) * NF) : (xbuf + (size_t)b * NF);
#pragma unroll
                    for (int j = 0; j < 4; j++) {
                        int c = tx * 4 + j;
                        catc[((size_t)(b * N + w)) * 80 + c] = xp[w * F + c];
                    }
                }
            }
        }
    } else {
        // P^2 tile (consumed only by the c-gate, launched after this kernel)
        int idx = bid - 208;
        int b = idx / 169, r = idx % 169;
        int w0 = (r % 13) * 16, v0 = (r / 13) * 16;
        const float* Pb = P + (size_t)b * PS * PS;
        float (*sA)[16][33] = (float(*)[16][33])(smem);
        float (*sB)[32][17] = (float(*)[32][17])(smem + 1056);
        int ty = tid >> 4, tx = tid & 15;
        int ar = tid >> 4, ac = (tid & 15) * 2;
        int br_ = tid >> 3, bc = (tid & 7) * 2;
        float2 av, bv;
        auto loadT = [&](int u0) {
            av = make_float2(0, 0); bv = make_float2(0, 0);
            int w = w0 + ar;
            if (w < N) av = *(const float2*)&Pb[(size_t)w * PS + u0 + ac];
            int u = u0 + br_;
            if (u < N) bv = *(const float2*)&Pb[(size_t)u * PS + v0 + bc];
        };
        loadT(0);
        int cur = 0;
        float acc = 0.f;
        for (int t = 0; t < 7; t++) {
            __syncthreads();
            sA[cur][ar][ac] = av.x; sA[cur][ar][ac + 1] = av.y;
            sB[cur][br_][bc] = bv.x; sB[cur][br_][bc + 1] = bv.y;
            if (t < 6) loadT((t + 1) * 32);
            __syncthreads();
#pragma unroll 8
            for (int u = 0; u < 32; u++) acc += sA[cur][ty][u] * sB[cur][u][tx];
            cur ^= 1;
        }
        int w = w0 + ty, v = v0 + tx;
        if (w < N && v < N) P2[(size_t)b * PS * PS + (size_t)w * PS + v] = acc;
    }
}

// ---------------- c-gate: dual-prop (P, P^2) phase A + GEMM (unchanged R14 code) ----------------
__global__ __launch_bounds__(256) void k_gate2(
    const float* __restrict__ cat, const float* __restrict__ P, const float* __restrict__ P2,
    const float* __restrict__ Wa, const float* __restrict__ ba,
    const float* __restrict__ Wb, const float* __restrict__ bb,
    int baseMode,
    const float* __restrict__ xseq, int tsel, const float* __restrict__ xbuf,
    float* __restrict__ zbuf, float* __restrict__ ricat,
    float* __restrict__ h,
    const float* __restrict__ target,
    const float* __restrict__ Wlong, const float* __restrict__ blong,
    const float* __restrict__ Wfus, const float* __restrict__ bfus,
    float* __restrict__ out) {
    int mode = baseMode + blockIdx.z;
    const float* W = (mode == 1) ? Wb : Wa;
    const float* bias = (mode == 1) ? bb : ba;
    int b = blockIdx.y, w0 = blockIdx.x * 16;
    int tid = threadIdx.x, ty = tid >> 4, tx = tid & 15;
    const float* Pb = P + (size_t)b * PS * PS;
    const float* Qb = P2 + (size_t)b * PS * PS;
    __shared__ float sC[16][241];
    __shared__ float sP[16][33], sQ[16][33];
    __shared__ float sX[32][81];
    __shared__ float sW[48][65];
    __shared__ float hrow[16][65], trow[16][65];
    // load g0 (80 cols)
    for (int l4 = tid; l4 < 320; l4 += 256) {
        int r = l4 / 20, c4 = (l4 % 20) * 4;
        int w = w0 + r;
        float4 v4 = make_float4(0, 0, 0, 0);
        if (w < N) v4 = *(const float4*)&cat[((size_t)(b * N + w)) * 80 + c4];
        sC[r][c4] = v4.x; sC[r][c4 + 1] = v4.y; sC[r][c4 + 2] = v4.z; sC[r][c4 + 3] = v4.w;
    }
    // phase A: dual prop over g0 -> g1 = a*g0 + P g0 ; g2 = a*g0 + a*(P g0) + P^2 g0
    float accP[5] = {0, 0, 0, 0, 0}, accQ[5] = {0, 0, 0, 0, 0};
    int prr = tid >> 4, prc = (tid & 15) * 2;
    int xrow = tid & 31, xc0 = (tid >> 5) * 10;
    float2 pv, qv;
    float2 xv[5];
    auto loadT = [&](int v0) {
        pv = make_float2(0, 0); qv = make_float2(0, 0);
        int w = w0 + prr;
        if (w < N) {
            pv = *(const float2*)&Pb[(size_t)w * PS + v0 + prc];
            qv = *(const float2*)&Qb[(size_t)w * PS + v0 + prc];
        }
        int v = v0 + xrow;
#pragma unroll
        for (int k = 0; k < 5; k++) xv[k] = make_float2(0, 0);
        if (v < N) {
            const float* src = &cat[((size_t)(b * N + v)) * 80 + xc0];
#pragma unroll
            for (int k = 0; k < 5; k++) xv[k] = *(const float2*)&src[k * 2];
        }
    };
    loadT(0);
    for (int t = 0; t < 7; t++) {
        __syncthreads();
        sP[prr][prc] = pv.x; sP[prr][prc + 1] = pv.y;
        sQ[prr][prc] = qv.x; sQ[prr][prc + 1] = qv.y;
#pragma unroll
        for (int k = 0; k < 5; k++) { sX[xrow][xc0 + 2 * k] = xv[k].x; sX[xrow][xc0 + 2 * k + 1] = xv[k].y; }
        if (t < 6) loadT((t + 1) * 32);
        __syncthreads();
#pragma unroll 8
        for (int v = 0; v < 32; v++) {
            float p = sP[ty][v], q = sQ[ty][v];
#pragma unroll
            for (int j = 0; j < 5; j++) {
                float x = sX[v][tx * 5 + j];
                accP[j] += p * x;
                accQ[j] += q * x;
            }
        }
    }
#pragma unroll
    for (int j = 0; j < 5; j++) {
        int c = tx * 5 + j;
        float g0 = sC[ty][c];
        sC[ty][80 + c]  = ALPHA * g0 + accP[j];
        sC[ty][160 + c] = ALPHA * g0 + ALPHA * accP[j] + accQ[j];
    }
    // phase B: GEMM over 240 cols with register prefetch
    float4 wv[3];
#pragma unroll
    for (int k = 0; k < 3; k++) wv[k] = *(const float4*)&W[(tid + k * 256) * 4];
    float ga[4];
#pragma unroll
    for (int j = 0; j < 4; j++) ga[j] = bias[tx * 4 + j];
    for (int ch = 0; ch < 5; ch++) {
        __syncthreads();
#pragma unroll
        for (int k = 0; k < 3; k++) {
            int l4 = tid + k * 256;
            int r = l4 >> 4, cc = (l4 & 15) * 4;
            sW[r][cc] = wv[k].x; sW[r][cc + 1] = wv[k].y; sW[r][cc + 2] = wv[k].z; sW[r][cc + 3] = wv[k].w;
        }
        if (ch < 4) {
#pragma unroll
            for (int k = 0; k < 3; k++) wv[k] = *(const float4*)&W[(size_t)(ch + 1) * 3072 + (tid + k * 256) * 4];
        }
        __syncthreads();
        int c0 = ch * 48;
#pragma unroll 8
        for (int cc = 0; cc < 48; cc++) {
            float cv = sC[ty][c0 + cc];
#pragma unroll
            for (int j = 0; j < 4; j++) ga[j] += cv * sW[cc][tx * 4 + j];
        }
    }
    int w = w0 + ty;
    bool valid = w < N;
    if (mode == 0) {
        if (valid) {
#pragma unroll
            for (int j = 0; j < 4; j++) zbuf[((size_t)(b * N + w)) * 64 + tx * 4 + j] = sigm(ga[j]);
        }
    } else if (mode == 1) {
        if (valid) {
#pragma unroll
            for (int j = 0; j < 4; j++) {
                int o = tx * 4 + j;
                ricat[((size_t)(b * N + w)) * 80 + 16 + o] = sigm(ga[j]) * h[((size_t)(b * N + w)) * 64 + o];
            }
            if (tx < 4) {
                const float* xp = (tsel >= 0) ? (xseq + ((size_t)(b * T + tsel)) * NF) : (xbuf + (size_t)b * NF);
#pragma unroll
                for (int j = 0; j < 4; j++) {
                    int c = tx * 4 + j;
                    ricat[((size_t)(b * N + w)) * 80 + c] = xp[w * F + c];
                }
            }
        }
    } else {
#pragma unroll
        for (int j = 0; j < 4; j++) {
            int o = tx * 4 + j;
            float cval = tanh_fast(ga[j]);
            float zv = 0.f, hv = 0.f;
            if (valid) { zv = zbuf[((size_t)(b * N + w)) * 64 + o]; hv = h[((size_t)(b * N + w)) * 64 + o]; }
            float hn = zv * hv + (1.f - zv) * cval;
            if (valid) h[((size_t)(b * N + w)) * 64 + o] = hn;
            hrow[ty][o] = valid ? hn : 0.f;
        }
        if (mode == 3) {
            for (int l = tid; l < 1024; l += 256) {
                int i = l >> 6, o = l & 63;
                int ww = w0 + i;
                trow[i][o] = (ww < N) ? target[((size_t)(b * N + ww)) * 64 + o] : 0.f;
            }
            __syncthreads();
            float lg = blong[tx];
            float fs = bfus[tx];
#pragma unroll 8
            for (int o = 0; o < 64; o++) {
                lg += hrow[ty][o] * Wlong[o * 16 + tx];
                fs += trow[ty][o] * Wfus[o * 16 + tx] + hrow[ty][o] * Wfus[(64 + o) * 16 + tx];
            }
            if (valid) {
                out[((size_t)1 * B * N + b * N + w) * 16 + tx] = lg;
                out[((size_t)2 * B * N + b * N + w) * 16 + tx] = fs;
            }
        }
    }
}

extern "C" void kernel_launch(void* const* d_in, const int* in_sizes, int n_in,
                              void* d_out, int out_size, void* d_ws, size_t ws_size,
                              hipStream_t stream) {
    const float* inp = (const float*)d_in[0];
    const float* adj = (const float*)d_in[1];
    const float* src_gen_w = (const float*)d_in[2];
    const float* src_gen_b = (const float*)d_in[3];
    const float* tgt_gen_w = (const float*)d_in[4];
    const float* tgt_gen_b = (const float*)d_in[5];
    const float* src_emb_w = (const float*)d_in[6];
    const float* src_emb_b = (const float*)d_in[7];
    const float* tgt_emb_w = (const float*)d_in[8];
    const float* tgt_emb_b = (const float*)d_in[9];
    const float* gru_z_w = (const float*)d_in[10];
    const float* gru_z_b = (const float*)d_in[11];
    const float* gru_r_w = (const float*)d_in[12];
    const float* gru_r_b = (const float*)d_in[13];
    const float* gru_c_w = (const float*)d_in[14];
    const float* gru_c_b = (const float*)d_in[15];
    const float* attn_q_w = (const float*)d_in[16];
    const float* attn_k_w = (const float*)d_in[17];
    const float* attn_k_b = (const float*)d_in[18];
    const float* attn_s_w = (const float*)d_in[19];
    const float* sgcn_w = (const float*)d_in[20];
    const float* sgcn_b = (const float*)d_in[21];
    const float* short_w = (const float*)d_in[22];
    const float* short_b = (const float*)d_in[23];
    const float* long_w = (const float*)d_in[24];
    const float* long_b = (const float*)d_in[25];
    const float* fus_w = (const float*)d_in[26];
    const float* fus_b = (const float*)d_in[27];
    float* out = (float*)d_out;

    float* ws = (float*)d_ws;
    size_t off = 0;
    auto A = [&](size_t n) { n = (n + 3) & ~(size_t)3; float* p = ws + off; off += n; return p; };
    float* Ts = A((size_t)PS * PS);
    float* A2 = A((size_t)PS * PS);
    float* sbuf = A((size_t)B * N * DH);
    float* tbuf = A((size_t)B * N * DH);
    float* P = A((size_t)B * PS * PS);
    float* P2 = A((size_t)B * PS * PS);
    float* catg = A((size_t)B * N * 80);
    float* catc = A((size_t)B * N * 80);
    float* pgbuf = A((size_t)B * N * 80);
    float* zb = A((size_t)B * N * 64);
    float* attnT = A((size_t)32 * PS * PS);
    float* x1 = A((size_t)32 * NF);
    float* xshort = A(BNF);
    size_t zero_begin = off;
    float* h = A((size_t)B * N * H);
    float* target = A((size_t)B * N * 64);
    float* rsum = A((size_t)32 * N);
    size_t zero_end = off;
    (void)ws_size; (void)in_sizes; (void)n_in; (void)out_size;

    hipMemsetAsync(h, 0, (zero_end - zero_begin) * sizeof(float), stream);
    // stage0 + cell0 cell_a fused (blocks 1785..1889)
    k_stage0<<<1889, 256, 0, stream>>>(adj, inp, attn_q_w, attn_k_w, attn_k_b, attn_s_w,
                                       src_emb_w, src_emb_b, tgt_emb_w, tgt_emb_b,
                                       src_gen_b, tgt_gen_b,
                                       Ts, A2, attnT, rsum, sbuf, tbuf, catg);

    auto run_cell = [&](int tsel, const float* xbuf, int finalFlag, int aux, bool skipA) {
        if (!skipA)
            k_cell_a<<<dim3(13, B, 2), 256, 0, stream>>>(h, Ts, A2, inp, tsel, xbuf,
                                                         src_gen_w, src_gen_b, tgt_gen_w, tgt_gen_b,
                                                         src_emb_w, src_emb_b, tgt_emb_w, tgt_emb_b, sbuf, tbuf, catg);
        k_cell_bP<<<dim3(26, B), 256, 0, stream>>>(sbuf, tbuf, adj, P);
        int extra = (aux == 1 || aux == 2) ? 416 : (aux == 3 ? 104 : 0);
        k_pg<<<520 + extra, 256, 0, stream>>>(P, catg, pgbuf, aux, attnT, rsum, Ts, inp, x1,
                                              sgcn_w, sgcn_b, target, short_w, short_b, out, xshort);
        k_gatezr<<<1560, 256, 0, stream>>>(catg, pgbuf, P, P2, gru_z_w, gru_z_b, gru_r_w, gru_r_b,
                                           inp, tsel, xbuf, zb, catc, h);
        k_gate2<<<dim3(13, B, 1), 256, 0, stream>>>(catc, P, P2, gru_c_w, gru_c_b, nullptr, nullptr, 2 + finalFlag,
                                                    nullptr, 0, nullptr, zb, nullptr, h,
                                                    target, long_w, long_b, fus_w, fus_b, out);
    };

    run_cell(0, nullptr, 0, 1, true);    // cell_a fused into stage0; + prop_xr aux
    run_cell(4, nullptr, 0, 2, false);   // + sgc2 aux
    run_cell(8, nullptr, 0, 3, false);   // + short head aux
    run_cell(12, nullptr, 0, 0, false);
    run_cell(16, nullptr, 0, 0, false);

    run_cell(-1, xshort, 1, 0, false);
}